// Round 2
// baseline (1089.531 us; speedup 1.0000x reference)
//
#include <hip/hip_runtime.h>
#include <hip/hip_fp16.h>

#define EMB 2048
#define NH 16
#define HD 128
#define BATCH 4
#define SEQ 2048
#define MROWS (BATCH * SEQ)   // 8192

typedef __attribute__((ext_vector_type(8))) _Float16 f16x8;
typedef __attribute__((ext_vector_type(4))) float f32x4;

typedef __attribute__((address_space(3))) unsigned int lds_u32_t;
typedef const __attribute__((address_space(1))) unsigned int glb_u32_t;

__device__ __forceinline__ void async_copy16(void* lds, const void* g) {
    __builtin_amdgcn_global_load_lds((glb_u32_t*)g, (lds_u32_t*)lds, 16, 0, 0);
}

// ---------------- fp32 -> fp16 convert ----------------
__global__ void cvt_f32_f16(const float* __restrict__ in, __half* __restrict__ out, int n4) {
    int i = blockIdx.x * 256 + threadIdx.x;
    if (i < n4) {
        float4 v = ((const float4*)in)[i];
        __half2 a, b;
        a.x = __float2half(v.x); a.y = __float2half(v.y);
        b.x = __float2half(v.z); b.y = __float2half(v.w);
        ((__half2*)out)[2 * i]     = a;
        ((__half2*)out)[2 * i + 1] = b;
    }
}

// ---------------- shared GEMM mainloop: C(128x128) = A * B^T, K = 2048 ----------------
__device__ __forceinline__ void gemm_mainloop(const __half* __restrict__ A,
                                              const __half* __restrict__ B,
                                              int m0, int n0,
                                              short* sA, short* sB,
                                              f32x4 acc[4][4]) {
    const int tid  = threadIdx.x;
    const int wave = tid >> 6;
    const int lane = tid & 63;
    const int wr = wave >> 1, wc = wave & 1;
    const int frow = lane & 15;
    const int fk   = (lane >> 4) * 8;
    const int r0 = tid >> 2;
    const int cb = (tid & 3) * 16;
    const char* gA = (const char*)A;
    const char* gB = (const char*)B;
    char* lA = (char*)sA;
    char* lB = (char*)sB;
    const int off0 = wave * 1024;
    const int off1 = 4096 + wave * 1024;

    for (int kt = 0; kt < EMB; kt += 32) {
        size_t kb = (size_t)kt * 2;
        async_copy16(lA + off0, gA + ((size_t)(m0 + r0) * EMB) * 2 + kb + cb);
        async_copy16(lA + off1, gA + ((size_t)(m0 + 64 + r0) * EMB) * 2 + kb + cb);
        async_copy16(lB + off0, gB + ((size_t)(n0 + r0) * EMB) * 2 + kb + cb);
        async_copy16(lB + off1, gB + ((size_t)(n0 + 64 + r0) * EMB) * 2 + kb + cb);
        __syncthreads();

        f16x8 af[4], bf[4];
#pragma unroll
        for (int i = 0; i < 4; i++)
            af[i] = *(const f16x8*)&sA[(wr * 64 + i * 16 + frow) * 32 + fk];
#pragma unroll
        for (int i = 0; i < 4; i++)
            bf[i] = *(const f16x8*)&sB[(wc * 64 + i * 16 + frow) * 32 + fk];
#pragma unroll
        for (int mi = 0; mi < 4; mi++)
#pragma unroll
            for (int ni = 0; ni < 4; ni++)
                acc[mi][ni] = __builtin_amdgcn_mfma_f32_16x16x32_f16(af[mi], bf[ni], acc[mi][ni], 0, 0, 0);
        __syncthreads();
    }
}

// ---------------- QKV projection + RoPE, writes (B,H,S,D) fp16 ----------------
__global__ __launch_bounds__(256) void gemm_qkv(const __half* __restrict__ X,
                                                const __half* __restrict__ Wq,
                                                const __half* __restrict__ Wk,
                                                const __half* __restrict__ Wv,
                                                __half* __restrict__ Q,
                                                __half* __restrict__ K,
                                                __half* __restrict__ V) {
    __shared__ short sA[128 * 32];
    __shared__ short sB[128 * 32];
    const int mblk = blockIdx.x;
    const int nb   = blockIdx.y;
    const int wsel = nb >> 4;
    const int nloc = (nb & 15) * 128;
    const __half* W = (wsel == 0) ? Wq : ((wsel == 1) ? Wk : Wv);

    f32x4 z = {0.f, 0.f, 0.f, 0.f};
    f32x4 acc[4][4];
#pragma unroll
    for (int i = 0; i < 4; i++)
#pragma unroll
        for (int j = 0; j < 4; j++) acc[i][j] = z;

    gemm_mainloop(X, W, mblk * 128, nloc, sA, sB, acc);

    const int lane = threadIdx.x & 63;
    const int wave = threadIdx.x >> 6;
    const int wr = wave >> 1, wc = wave & 1;
    const int q4 = lane >> 4;
    __half* Obuf = (wsel == 0) ? Q : ((wsel == 1) ? K : V);
    const bool rope = (wsel < 2);

#pragma unroll
    for (int ni = 0; ni < 4; ni++) {
        int n = nloc + wc * 64 + ni * 16 + (lane & 15);
        int h = n >> 7, d = n & 127;
        float invf = rope ? __expf(-((float)(d & ~1)) * (9.210340371976184f / 128.0f)) : 0.f;
#pragma unroll
        for (int mi = 0; mi < 4; mi++) {
#pragma unroll
            for (int r = 0; r < 4; r++) {
                int m = mblk * 128 + wr * 64 + mi * 16 + q4 * 4 + r;
                int b = m >> 11, s = m & 2047;
                float v = acc[mi][ni][r];
                float res;
                if (rope) {
                    float p = __shfl_xor(v, 1);
                    float ang = (float)s * invf;
                    float sn, cs;
                    __sincosf(ang, &sn, &cs);
                    if ((lane & 1) == 0) res = v * cs - p * sn;
                    else                 res = v * cs + p * sn;
                } else {
                    res = v;
                }
                float pr = __shfl_xor(res, 1);
                if ((lane & 1) == 0) {
                    __half2 hv;
                    hv.x = __float2half(res);
                    hv.y = __float2half(pr);
                    size_t off = ((size_t)(b * NH + h) * SEQ + s) * HD + d;
                    *(__half2*)(Obuf + off) = hv;
                }
            }
        }
    }
}

// ---------------- V transpose: V[bh][s][d] -> Vt[bh][d][s] ----------------
__global__ __launch_bounds__(256) void transpose_v(const __half* __restrict__ V,
                                                   __half* __restrict__ Vt) {
    __shared__ short t[64 * 65];
    const int st = blockIdx.x & 31;
    const int dt = (blockIdx.x >> 5) & 1;
    const int bh = blockIdx.y;
    const int tid = threadIdx.x;
    const __half* Vh = V + (size_t)bh * SEQ * HD;
    __half* Vo = Vt + (size_t)bh * SEQ * HD;
#pragma unroll
    for (int k = 0; k < 2; k++) {
        int id = k * 256 + tid;
        int r = id >> 3, c8 = id & 7;
        f16x8 v = *(const f16x8*)(Vh + (size_t)(st * 64 + r) * HD + dt * 64 + c8 * 8);
#pragma unroll
        for (int e = 0; e < 8; e++) t[r * 65 + c8 * 8 + e] = ((short*)&v)[e];
    }
    __syncthreads();
#pragma unroll
    for (int k = 0; k < 2; k++) {
        int id = k * 256 + tid;
        int dr = id >> 3, sc8 = id & 7;
        f16x8 v;
#pragma unroll
        for (int e = 0; e < 8; e++) ((short*)&v)[e] = t[(sc8 * 8 + e) * 65 + dr];
        *(f16x8*)(Vo + (size_t)(dt * 64 + dr) * SEQ + st * 64 + sc8 * 8) = v;
    }
}

// ---------------- causal flash attention v4 ----------------
// BQ=64 (16 rows/wave), BK=64. LDS 40KB: sK 16KB + sV 16KB + sP 8KB.
// Pair-balanced grid: block x in [0,16) handles q-tiles (31-x) then (x),
// so every block does exactly 33 K-tile iterations -> 1024 uniform blocks
// = exactly 4 blocks/CU resident, zero drain tail (prev: avg occupancy
// 16% of 37% nominal due to late heavy blocks draining alone).
// 4 blocks/CU (launch_bounds 256,4; 4 x 40KB = 160KB exact LDS fit).
// setprio(1) around MFMA clusters (T5; blocks now interleave per SIMD).
__global__ __launch_bounds__(256, 4) void attn_kernel(const __half* __restrict__ Q,
                                                      const __half* __restrict__ K,
                                                      const __half* __restrict__ Vt,
                                                      __half* __restrict__ CTX) {
    __shared__ short sK[64 * 128];      // K tile: 64 keys x 128 d, 16-chunk swizzle
    __shared__ short sV[128 * 64];      // V^T tile: 128 d x 64 keys, 8-chunk swizzle
    __shared__ short sP[4][16 * 64];    // per-wave P scratch
    const int pairx = blockIdx.x;       // 0..15
    const int bh = blockIdx.y;
    const int b = bh >> 4, h = bh & 15;
    const int tid = threadIdx.x;
    const int wave = tid >> 6, lane = tid & 63;
    const int fr = lane & 15, q4 = lane >> 4;
    const size_t headoff = (size_t)bh * SEQ * HD;
    const __half* Qh = Q + headoff;
    const __half* Kh = K + headoff;
    const __half* Vth = Vt + headoff;   // [d][s]
    short* sPw = &sP[wave][0];

    f32x4 z = {0.f, 0.f, 0.f, 0.f};

#pragma unroll 1
    for (int pass = 0; pass < 2; pass++) {
        const int qt = pass ? pairx : (31 - pairx);   // heavy tile first
        const int nk = qt + 1;

        // Q fragments (wave rows qt*64 + wave*16 + fr), scale folded
        f16x8 qf[4];
#pragma unroll
        for (int ds = 0; ds < 4; ds++) {
            qf[ds] = *(const f16x8*)(Qh + (size_t)(qt * 64 + wave * 16 + fr) * HD + ds * 32 + q4 * 8);
            qf[ds] = qf[ds] * (_Float16)0.08838834764831845f;
        }

        f32x4 accO[8];
#pragma unroll
        for (int i = 0; i < 8; i++) accO[i] = z;
        float mrow[4], lrow[4];
#pragma unroll
        for (int r = 0; r < 4; r++) { mrow[r] = -INFINITY; lrow[r] = 0.f; }

        // prefetch registers (tile 0)
        f16x8 kpre[4], vpre[4];
#pragma unroll
        for (int j = 0; j < 4; j++) {
            int id = j * 256 + tid;
            int row = id >> 4, c = id & 15;
            kpre[j] = *(const f16x8*)(Kh + (size_t)row * HD + c * 8);
        }
#pragma unroll
        for (int j = 0; j < 4; j++) {
            int id = j * 256 + tid;
            int d = id >> 3, c = id & 7;
            vpre[j] = *(const f16x8*)(Vth + (size_t)d * SEQ + c * 8);
        }

        for (int kt = 0; kt < nk; kt++) {
            __syncthreads();   // barrier A: previous compute done reading sK/sV
            // ---- VGPR -> LDS (swizzled) ----
#pragma unroll
            for (int j = 0; j < 4; j++) {
                int id = j * 256 + tid;
                int row = id >> 4, c = id & 15;
                *(f16x8*)&sK[row * 128 + ((c ^ (row & 15)) * 8)] = kpre[j];
            }
#pragma unroll
            for (int j = 0; j < 4; j++) {
                int id = j * 256 + tid;
                int d = id >> 3, c = id & 7;
                *(f16x8*)&sV[d * 64 + ((c ^ (d & 7)) * 8)] = vpre[j];
            }
            __syncthreads();   // barrier B: tiles visible

            // ---- issue next tile's global loads (overlap with compute) ----
            if (kt + 1 < nk) {
                int kbase = (kt + 1) * 64;
#pragma unroll
                for (int j = 0; j < 4; j++) {
                    int id = j * 256 + tid;
                    int row = id >> 4, c = id & 15;
                    kpre[j] = *(const f16x8*)(Kh + (size_t)(kbase + row) * HD + c * 8);
                }
#pragma unroll
                for (int j = 0; j < 4; j++) {
                    int id = j * 256 + tid;
                    int d = id >> 3, c = id & 7;
                    vpre[j] = *(const f16x8*)(Vth + (size_t)d * SEQ + kbase + c * 8);
                }
            }

            // ---- S = Q K^T (16 rows x 64 cols per wave) ----
            f32x4 accS[4];
#pragma unroll
            for (int i = 0; i < 4; i++) accS[i] = z;
            __builtin_amdgcn_s_setprio(1);
#pragma unroll
            for (int ds = 0; ds < 4; ds++) {
                f16x8 kf[4];
#pragma unroll
                for (int ni = 0; ni < 4; ni++)
                    kf[ni] = *(const f16x8*)&sK[(ni * 16 + fr) * 128 + (((ds * 4 + q4) ^ fr) * 8)];
#pragma unroll
                for (int ni = 0; ni < 4; ni++)
                    accS[ni] = __builtin_amdgcn_mfma_f32_16x16x32_f16(qf[ds], kf[ni], accS[ni], 0, 0, 0);
            }
            __builtin_amdgcn_s_setprio(0);

            // ---- causal mask (diagonal tile only) ----
            if (kt == qt) {
#pragma unroll
                for (int ni = 0; ni < 4; ni++) {
                    int kcol = ni * 16 + fr;
#pragma unroll
                    for (int r = 0; r < 4; r++) {
                        int qrow = wave * 16 + q4 * 4 + r;
                        if (kcol > qrow) accS[ni][r] = -INFINITY;
                    }
                }
            }

            // ---- online softmax ----
#pragma unroll
            for (int r = 0; r < 4; r++) {
                float mold = mrow[r];
                float mx = mold;
#pragma unroll
                for (int ni = 0; ni < 4; ni++) mx = fmaxf(mx, accS[ni][r]);
#pragma unroll
                for (int off = 1; off < 16; off <<= 1)
                    mx = fmaxf(mx, __shfl_xor(mx, off));
                float alpha = __expf(mold - mx);
                mrow[r] = mx;
                float rs = 0.f;
#pragma unroll
                for (int ni = 0; ni < 4; ni++) {
                    float p = __expf(accS[ni][r] - mx);
                    rs += p;
                    accS[ni][r] = p;
                }
#pragma unroll
                for (int off = 1; off < 16; off <<= 1)
                    rs += __shfl_xor(rs, off);
                lrow[r] = lrow[r] * alpha + rs;
#pragma unroll
                for (int di = 0; di < 8; di++)
                    accO[di][r] *= alpha;
            }

            // ---- P -> wave-private scratch (no barrier; intra-wave ordering) ----
#pragma unroll
            for (int ni = 0; ni < 4; ni++)
#pragma unroll
                for (int r = 0; r < 4; r++) {
                    float p = accS[ni][r];
                    float pp = __shfl_xor(p, 1);
                    if ((lane & 1) == 0) {
                        int row = q4 * 4 + r;
                        int col = ni * 16 + fr;                 // even
                        int xc = (col >> 3) ^ (row & 7);
                        __half2 h2;
                        h2.x = __float2half(p);
                        h2.y = __float2half(pp);
                        *(__half2*)&sPw[row * 64 + xc * 8 + (col & 7)] = h2;
                    }
                }

            // ---- O += P V ----
            __builtin_amdgcn_s_setprio(1);
#pragma unroll
            for (int ns = 0; ns < 2; ns++) {
                f16x8 pf = *(const f16x8*)&sPw[fr * 64 + (((ns * 4 + q4) ^ (fr & 7)) * 8)];
#pragma unroll
                for (int di = 0; di < 8; di++) {
                    f16x8 vf = *(const f16x8*)&sV[(di * 16 + fr) * 64 + (((ns * 4 + q4) ^ (fr & 7)) * 8)];
                    accO[di] = __builtin_amdgcn_mfma_f32_16x16x32_f16(pf, vf, accO[di], 0, 0, 0);
                }
            }
            __builtin_amdgcn_s_setprio(0);
            // no barrier here: next iteration's barrier A protects sK/sV
        }

        // ---- epilogue ----
        float linv[4];
#pragma unroll
        for (int r = 0; r < 4; r++) linv[r] = 1.f / lrow[r];

#pragma unroll
        for (int di = 0; di < 8; di++)
#pragma unroll
            for (int r = 0; r < 4; r++) {
                float o = accO[di][r] * linv[r];
                float po = __shfl_xor(o, 1);
                if ((lane & 1) == 0) {
                    int srow = qt * 64 + wave * 16 + q4 * 4 + r;
                    int d = di * 16 + fr;  // even
                    size_t off = ((size_t)(b * SEQ + srow)) * EMB + h * HD + d;
                    __half2 h2;
                    h2.x = __float2half(o);
                    h2.y = __float2half(po);
                    *(__half2*)&CTX[off] = h2;
                }
            }
    }
}

// ---------------- output projection: out(fp32) = CTX * Wo^T ----------------
__global__ __launch_bounds__(256) void gemm_out(const __half* __restrict__ CTX,
                                                const __half* __restrict__ Wo,
                                                float* __restrict__ out) {
    __shared__ short sA[128 * 32];
    __shared__ short sB[128 * 32];
    f32x4 z = {0.f, 0.f, 0.f, 0.f};
    f32x4 acc[4][4];
#pragma unroll
    for (int i = 0; i < 4; i++)
#pragma unroll
        for (int j = 0; j < 4; j++) acc[i][j] = z;

    gemm_mainloop(CTX, Wo, blockIdx.x * 128, blockIdx.y * 128, sA, sB, acc);

    const int lane = threadIdx.x & 63;
    const int wave = threadIdx.x >> 6;
    const int wr = wave >> 1, wc = wave & 1;
    const int q4 = lane >> 4;
#pragma unroll
    for (int mi = 0; mi < 4; mi++)
#pragma unroll
        for (int ni = 0; ni < 4; ni++)
#pragma unroll
            for (int r = 0; r < 4; r++) {
                int m = blockIdx.x * 128 + wr * 64 + mi * 16 + q4 * 4 + r;
                int n = blockIdx.y * 128 + wc * 64 + ni * 16 + (lane & 15);
                out[(size_t)m * EMB + n] = acc[mi][ni][r];
            }
}

extern "C" void kernel_launch(void* const* d_in, const int* in_sizes, int n_in,
                              void* d_out, int out_size, void* d_ws, size_t ws_size,
                              hipStream_t stream) {
    const float* x  = (const float*)d_in[0];
    const float* Wq = (const float*)d_in[1];
    const float* Wk = (const float*)d_in[2];
    const float* Wv = (const float*)d_in[3];
    const float* Wo = (const float*)d_in[4];
    float* out = (float*)d_out;

    char* ws = (char*)d_ws;
    size_t off = 0;
    const size_t QKV_ELEMS = (size_t)MROWS * EMB;   // 16777216
    __half* Xh  = (__half*)(ws + off); off += QKV_ELEMS * 2;          // reused as CTX
    __half* Wqh = (__half*)(ws + off); off += (size_t)EMB * EMB * 2;
    __half* Wkh = (__half*)(ws + off); off += (size_t)EMB * EMB * 2;
    __half* Wvh = (__half*)(ws + off); off += (size_t)EMB * EMB * 2;
    __half* Woh = (__half*)(ws + off); off += (size_t)EMB * EMB * 2;
    __half* Qb  = (__half*)(ws + off); off += QKV_ELEMS * 2;
    __half* Kb  = (__half*)(ws + off); off += QKV_ELEMS * 2;
    __half* Vb  = (__half*)(ws + off); off += QKV_ELEMS * 2;
    __half* Vtb = (__half*)(ws + off); off += QKV_ELEMS * 2;
    __half* Cb  = Xh;   // X dead after gemm_qkv

    cvt_f32_f16<<<16384, 256, 0, stream>>>(x,  Xh,  4194304);
    cvt_f32_f16<<<4096,  256, 0, stream>>>(Wq, Wqh, 1048576);
    cvt_f32_f16<<<4096,  256, 0, stream>>>(Wk, Wkh, 1048576);
    cvt_f32_f16<<<4096,  256, 0, stream>>>(Wv, Wvh, 1048576);
    cvt_f32_f16<<<4096,  256, 0, stream>>>(Wo, Woh, 1048576);

    gemm_qkv<<<dim3(64, 48), 256, 0, stream>>>(Xh, Wqh, Wkh, Wvh, Qb, Kb, Vb);
    transpose_v<<<dim3(64, 64), 256, 0, stream>>>(Vb, Vtb);
    attn_kernel<<<dim3(16, 64), 256, 0, stream>>>(Qb, Kb, Vtb, Cb);
    gemm_out<<<dim3(64, 16), 256, 0, stream>>>(Cb, Woh, out);
}

// Round 3
// 857.143 us; speedup vs baseline: 1.2711x; 1.2711x over previous
//
#include <hip/hip_runtime.h>
#include <hip/hip_fp16.h>

#define EMB 2048
#define NH 16
#define HD 128
#define BATCH 4
#define SEQ 2048
#define MROWS (BATCH * SEQ)   // 8192

typedef __attribute__((ext_vector_type(8))) _Float16 f16x8;
typedef __attribute__((ext_vector_type(4))) float f32x4;

typedef __attribute__((address_space(3))) unsigned int lds_u32_t;
typedef const __attribute__((address_space(1))) unsigned int glb_u32_t;

__device__ __forceinline__ void async_copy16(void* lds, const void* g) {
    __builtin_amdgcn_global_load_lds((glb_u32_t*)g, (lds_u32_t*)lds, 16, 0, 0);
}

// ---------------- fp32 -> fp16 convert ----------------
__global__ void cvt_f32_f16(const float* __restrict__ in, __half* __restrict__ out, int n4) {
    int i = blockIdx.x * 256 + threadIdx.x;
    if (i < n4) {
        float4 v = ((const float4*)in)[i];
        __half2 a, b;
        a.x = __float2half(v.x); a.y = __float2half(v.y);
        b.x = __float2half(v.z); b.y = __float2half(v.w);
        ((__half2*)out)[2 * i]     = a;
        ((__half2*)out)[2 * i + 1] = b;
    }
}

// ---------------- shared GEMM mainloop: C(128x128) = A * B^T, K = 2048 ----------------
__device__ __forceinline__ void gemm_mainloop(const __half* __restrict__ A,
                                              const __half* __restrict__ B,
                                              int m0, int n0,
                                              short* sA, short* sB,
                                              f32x4 acc[4][4]) {
    const int tid  = threadIdx.x;
    const int wave = tid >> 6;
    const int lane = tid & 63;
    const int wr = wave >> 1, wc = wave & 1;
    const int frow = lane & 15;
    const int fk   = (lane >> 4) * 8;
    const int r0 = tid >> 2;
    const int cb = (tid & 3) * 16;
    const char* gA = (const char*)A;
    const char* gB = (const char*)B;
    char* lA = (char*)sA;
    char* lB = (char*)sB;
    const int off0 = wave * 1024;
    const int off1 = 4096 + wave * 1024;

    for (int kt = 0; kt < EMB; kt += 32) {
        size_t kb = (size_t)kt * 2;
        async_copy16(lA + off0, gA + ((size_t)(m0 + r0) * EMB) * 2 + kb + cb);
        async_copy16(lA + off1, gA + ((size_t)(m0 + 64 + r0) * EMB) * 2 + kb + cb);
        async_copy16(lB + off0, gB + ((size_t)(n0 + r0) * EMB) * 2 + kb + cb);
        async_copy16(lB + off1, gB + ((size_t)(n0 + 64 + r0) * EMB) * 2 + kb + cb);
        __syncthreads();

        f16x8 af[4], bf[4];
#pragma unroll
        for (int i = 0; i < 4; i++)
            af[i] = *(const f16x8*)&sA[(wr * 64 + i * 16 + frow) * 32 + fk];
#pragma unroll
        for (int i = 0; i < 4; i++)
            bf[i] = *(const f16x8*)&sB[(wc * 64 + i * 16 + frow) * 32 + fk];
#pragma unroll
        for (int mi = 0; mi < 4; mi++)
#pragma unroll
            for (int ni = 0; ni < 4; ni++)
                acc[mi][ni] = __builtin_amdgcn_mfma_f32_16x16x32_f16(af[mi], bf[ni], acc[mi][ni], 0, 0, 0);
        __syncthreads();
    }
}

// ---------------- QKV projection + RoPE, writes (B,H,S,D) fp16 ----------------
__global__ __launch_bounds__(256) void gemm_qkv(const __half* __restrict__ X,
                                                const __half* __restrict__ Wq,
                                                const __half* __restrict__ Wk,
                                                const __half* __restrict__ Wv,
                                                __half* __restrict__ Q,
                                                __half* __restrict__ K,
                                                __half* __restrict__ V) {
    __shared__ short sA[128 * 32];
    __shared__ short sB[128 * 32];
    const int mblk = blockIdx.x;
    const int nb   = blockIdx.y;
    const int wsel = nb >> 4;
    const int nloc = (nb & 15) * 128;
    const __half* W = (wsel == 0) ? Wq : ((wsel == 1) ? Wk : Wv);

    f32x4 z = {0.f, 0.f, 0.f, 0.f};
    f32x4 acc[4][4];
#pragma unroll
    for (int i = 0; i < 4; i++)
#pragma unroll
        for (int j = 0; j < 4; j++) acc[i][j] = z;

    gemm_mainloop(X, W, mblk * 128, nloc, sA, sB, acc);

    const int lane = threadIdx.x & 63;
    const int wave = threadIdx.x >> 6;
    const int wr = wave >> 1, wc = wave & 1;
    const int q4 = lane >> 4;
    __half* Obuf = (wsel == 0) ? Q : ((wsel == 1) ? K : V);
    const bool rope = (wsel < 2);

#pragma unroll
    for (int ni = 0; ni < 4; ni++) {
        int n = nloc + wc * 64 + ni * 16 + (lane & 15);
        int h = n >> 7, d = n & 127;
        float invf = rope ? __expf(-((float)(d & ~1)) * (9.210340371976184f / 128.0f)) : 0.f;
#pragma unroll
        for (int mi = 0; mi < 4; mi++) {
#pragma unroll
            for (int r = 0; r < 4; r++) {
                int m = mblk * 128 + wr * 64 + mi * 16 + q4 * 4 + r;
                int b = m >> 11, s = m & 2047;
                float v = acc[mi][ni][r];
                float res;
                if (rope) {
                    float p = __shfl_xor(v, 1);
                    float ang = (float)s * invf;
                    float sn, cs;
                    __sincosf(ang, &sn, &cs);
                    if ((lane & 1) == 0) res = v * cs - p * sn;
                    else                 res = v * cs + p * sn;
                } else {
                    res = v;
                }
                float pr = __shfl_xor(res, 1);
                if ((lane & 1) == 0) {
                    __half2 hv;
                    hv.x = __float2half(res);
                    hv.y = __float2half(pr);
                    size_t off = ((size_t)(b * NH + h) * SEQ + s) * HD + d;
                    *(__half2*)(Obuf + off) = hv;
                }
            }
        }
    }
}

// ---------------- V transpose: V[bh][s][d] -> Vt[bh][d][s] ----------------
__global__ __launch_bounds__(256) void transpose_v(const __half* __restrict__ V,
                                                   __half* __restrict__ Vt) {
    __shared__ short t[64 * 65];
    const int st = blockIdx.x & 31;
    const int dt = (blockIdx.x >> 5) & 1;
    const int bh = blockIdx.y;
    const int tid = threadIdx.x;
    const __half* Vh = V + (size_t)bh * SEQ * HD;
    __half* Vo = Vt + (size_t)bh * SEQ * HD;
#pragma unroll
    for (int k = 0; k < 2; k++) {
        int id = k * 256 + tid;
        int r = id >> 3, c8 = id & 7;
        f16x8 v = *(const f16x8*)(Vh + (size_t)(st * 64 + r) * HD + dt * 64 + c8 * 8);
#pragma unroll
        for (int e = 0; e < 8; e++) t[r * 65 + c8 * 8 + e] = ((short*)&v)[e];
    }
    __syncthreads();
#pragma unroll
    for (int k = 0; k < 2; k++) {
        int id = k * 256 + tid;
        int dr = id >> 3, sc8 = id & 7;
        f16x8 v;
#pragma unroll
        for (int e = 0; e < 8; e++) ((short*)&v)[e] = t[(sc8 * 8 + e) * 65 + dr];
        *(f16x8*)(Vo + (size_t)(dt * 64 + dr) * SEQ + st * 64 + sc8 * 8) = v;
    }
}

// ---------------- causal flash attention v5 ----------------
// BQ=64 (16 rows/wave), BK=64. LDS 40KB: sK 16KB + sV 16KB + sP 8KB.
// Pair-balanced grid: 1024 blocks, each handles q-tiles (31-x) then (x)
// = exactly 33 K-tile iterations -> uniform blocks, no drain tail.
// launch_bounds(256,3): round-2's (256,4) forced VGPR 84->64 and spilled
// (WRITE_SIZE 51->487MB of scratch). (256,3) keeps ~84 VGPR (no spill);
// since 84 <= 128 the HW still fits 4 blocks/CU (LDS 4x40KB = 160KB exact).
// XCD swizzle: dispatch-id % 8 -> XCD; map each XCD to 8 exclusive heads
// so its L2 working set is 8MB streamed instead of all 64 heads.
__global__ __launch_bounds__(256, 3) void attn_kernel(const __half* __restrict__ Q,
                                                      const __half* __restrict__ K,
                                                      const __half* __restrict__ Vt,
                                                      __half* __restrict__ CTX) {
    __shared__ short sK[64 * 128];      // K tile: 64 keys x 128 d, 16-chunk swizzle
    __shared__ short sV[128 * 64];      // V^T tile: 128 d x 64 keys, 8-chunk swizzle
    __shared__ short sP[4][16 * 64];    // per-wave P scratch
    // XCD-aware work mapping: disp%8 = XCD (round-robin dispatch assumption);
    // give XCD c the contiguous work range [c*128, c*128+128) = heads [8c, 8c+8).
    const int disp  = blockIdx.y * 16 + blockIdx.x;   // 0..1023, dispatch order
    const int wid   = (disp & 7) * 128 + (disp >> 3); // bijective, nwg%8==0
    const int pairx = wid & 15;                       // 0..15
    const int bh    = wid >> 4;                       // 0..63
    const int b = bh >> 4, h = bh & 15;
    const int tid = threadIdx.x;
    const int wave = tid >> 6, lane = tid & 63;
    const int fr = lane & 15, q4 = lane >> 4;
    const size_t headoff = (size_t)bh * SEQ * HD;
    const __half* Qh = Q + headoff;
    const __half* Kh = K + headoff;
    const __half* Vth = Vt + headoff;   // [d][s]
    short* sPw = &sP[wave][0];

    f32x4 z = {0.f, 0.f, 0.f, 0.f};

#pragma unroll 1
    for (int pass = 0; pass < 2; pass++) {
        const int qt = pass ? pairx : (31 - pairx);   // heavy tile first
        const int nk = qt + 1;

        // Q fragments (wave rows qt*64 + wave*16 + fr), scale folded
        f16x8 qf[4];
#pragma unroll
        for (int ds = 0; ds < 4; ds++) {
            qf[ds] = *(const f16x8*)(Qh + (size_t)(qt * 64 + wave * 16 + fr) * HD + ds * 32 + q4 * 8);
            qf[ds] = qf[ds] * (_Float16)0.08838834764831845f;
        }

        f32x4 accO[8];
#pragma unroll
        for (int i = 0; i < 8; i++) accO[i] = z;
        float mrow[4], lrow[4];
#pragma unroll
        for (int r = 0; r < 4; r++) { mrow[r] = -INFINITY; lrow[r] = 0.f; }

        // prefetch registers (tile 0)
        f16x8 kpre[4], vpre[4];
#pragma unroll
        for (int j = 0; j < 4; j++) {
            int id = j * 256 + tid;
            int row = id >> 4, c = id & 15;
            kpre[j] = *(const f16x8*)(Kh + (size_t)row * HD + c * 8);
        }
#pragma unroll
        for (int j = 0; j < 4; j++) {
            int id = j * 256 + tid;
            int d = id >> 3, c = id & 7;
            vpre[j] = *(const f16x8*)(Vth + (size_t)d * SEQ + c * 8);
        }

        for (int kt = 0; kt < nk; kt++) {
            __syncthreads();   // barrier A: previous compute done reading sK/sV
            // ---- VGPR -> LDS (swizzled) ----
#pragma unroll
            for (int j = 0; j < 4; j++) {
                int id = j * 256 + tid;
                int row = id >> 4, c = id & 15;
                *(f16x8*)&sK[row * 128 + ((c ^ (row & 15)) * 8)] = kpre[j];
            }
#pragma unroll
            for (int j = 0; j < 4; j++) {
                int id = j * 256 + tid;
                int d = id >> 3, c = id & 7;
                *(f16x8*)&sV[d * 64 + ((c ^ (d & 7)) * 8)] = vpre[j];
            }
            __syncthreads();   // barrier B: tiles visible

            // ---- issue next tile's global loads (overlap with compute) ----
            if (kt + 1 < nk) {
                int kbase = (kt + 1) * 64;
#pragma unroll
                for (int j = 0; j < 4; j++) {
                    int id = j * 256 + tid;
                    int row = id >> 4, c = id & 15;
                    kpre[j] = *(const f16x8*)(Kh + (size_t)(kbase + row) * HD + c * 8);
                }
#pragma unroll
                for (int j = 0; j < 4; j++) {
                    int id = j * 256 + tid;
                    int d = id >> 3, c = id & 7;
                    vpre[j] = *(const f16x8*)(Vth + (size_t)d * SEQ + kbase + c * 8);
                }
            }

            // ---- S = Q K^T (16 rows x 64 cols per wave) ----
            f32x4 accS[4];
#pragma unroll
            for (int i = 0; i < 4; i++) accS[i] = z;
            __builtin_amdgcn_s_setprio(1);
#pragma unroll
            for (int ds = 0; ds < 4; ds++) {
                f16x8 kf[4];
#pragma unroll
                for (int ni = 0; ni < 4; ni++)
                    kf[ni] = *(const f16x8*)&sK[(ni * 16 + fr) * 128 + (((ds * 4 + q4) ^ fr) * 8)];
#pragma unroll
                for (int ni = 0; ni < 4; ni++)
                    accS[ni] = __builtin_amdgcn_mfma_f32_16x16x32_f16(qf[ds], kf[ni], accS[ni], 0, 0, 0);
            }
            __builtin_amdgcn_s_setprio(0);

            // ---- causal mask (diagonal tile only) ----
            if (kt == qt) {
#pragma unroll
                for (int ni = 0; ni < 4; ni++) {
                    int kcol = ni * 16 + fr;
#pragma unroll
                    for (int r = 0; r < 4; r++) {
                        int qrow = wave * 16 + q4 * 4 + r;
                        if (kcol > qrow) accS[ni][r] = -INFINITY;
                    }
                }
            }

            // ---- online softmax ----
#pragma unroll
            for (int r = 0; r < 4; r++) {
                float mold = mrow[r];
                float mx = mold;
#pragma unroll
                for (int ni = 0; ni < 4; ni++) mx = fmaxf(mx, accS[ni][r]);
#pragma unroll
                for (int off = 1; off < 16; off <<= 1)
                    mx = fmaxf(mx, __shfl_xor(mx, off));
                float alpha = __expf(mold - mx);
                mrow[r] = mx;
                float rs = 0.f;
#pragma unroll
                for (int ni = 0; ni < 4; ni++) {
                    float p = __expf(accS[ni][r] - mx);
                    rs += p;
                    accS[ni][r] = p;
                }
#pragma unroll
                for (int off = 1; off < 16; off <<= 1)
                    rs += __shfl_xor(rs, off);
                lrow[r] = lrow[r] * alpha + rs;
#pragma unroll
                for (int di = 0; di < 8; di++)
                    accO[di][r] *= alpha;
            }

            // ---- P -> wave-private scratch (no barrier; intra-wave ordering) ----
#pragma unroll
            for (int ni = 0; ni < 4; ni++)
#pragma unroll
                for (int r = 0; r < 4; r++) {
                    float p = accS[ni][r];
                    float pp = __shfl_xor(p, 1);
                    if ((lane & 1) == 0) {
                        int row = q4 * 4 + r;
                        int col = ni * 16 + fr;                 // even
                        int xc = (col >> 3) ^ (row & 7);
                        __half2 h2;
                        h2.x = __float2half(p);
                        h2.y = __float2half(pp);
                        *(__half2*)&sPw[row * 64 + xc * 8 + (col & 7)] = h2;
                    }
                }

            // ---- O += P V ----
            __builtin_amdgcn_s_setprio(1);
#pragma unroll
            for (int ns = 0; ns < 2; ns++) {
                f16x8 pf = *(const f16x8*)&sPw[fr * 64 + (((ns * 4 + q4) ^ (fr & 7)) * 8)];
#pragma unroll
                for (int di = 0; di < 8; di++) {
                    f16x8 vf = *(const f16x8*)&sV[(di * 16 + fr) * 64 + (((ns * 4 + q4) ^ (fr & 7)) * 8)];
                    accO[di] = __builtin_amdgcn_mfma_f32_16x16x32_f16(pf, vf, accO[di], 0, 0, 0);
                }
            }
            __builtin_amdgcn_s_setprio(0);
            // no barrier here: next iteration's barrier A protects sK/sV
        }

        // ---- epilogue ----
        float linv[4];
#pragma unroll
        for (int r = 0; r < 4; r++) linv[r] = 1.f / lrow[r];

#pragma unroll
        for (int di = 0; di < 8; di++)
#pragma unroll
            for (int r = 0; r < 4; r++) {
                float o = accO[di][r] * linv[r];
                float po = __shfl_xor(o, 1);
                if ((lane & 1) == 0) {
                    int srow = qt * 64 + wave * 16 + q4 * 4 + r;
                    int d = di * 16 + fr;  // even
                    size_t off = ((size_t)(b * SEQ + srow)) * EMB + h * HD + d;
                    __half2 h2;
                    h2.x = __float2half(o);
                    h2.y = __float2half(po);
                    *(__half2*)&CTX[off] = h2;
                }
            }
    }
}

// ---------------- output projection: out(fp32) = CTX * Wo^T ----------------
__global__ __launch_bounds__(256) void gemm_out(const __half* __restrict__ CTX,
                                                const __half* __restrict__ Wo,
                                                float* __restrict__ out) {
    __shared__ short sA[128 * 32];
    __shared__ short sB[128 * 32];
    f32x4 z = {0.f, 0.f, 0.f, 0.f};
    f32x4 acc[4][4];
#pragma unroll
    for (int i = 0; i < 4; i++)
#pragma unroll
        for (int j = 0; j < 4; j++) acc[i][j] = z;

    gemm_mainloop(CTX, Wo, blockIdx.x * 128, blockIdx.y * 128, sA, sB, acc);

    const int lane = threadIdx.x & 63;
    const int wave = threadIdx.x >> 6;
    const int wr = wave >> 1, wc = wave & 1;
    const int q4 = lane >> 4;
#pragma unroll
    for (int mi = 0; mi < 4; mi++)
#pragma unroll
        for (int ni = 0; ni < 4; ni++)
#pragma unroll
            for (int r = 0; r < 4; r++) {
                int m = blockIdx.x * 128 + wr * 64 + mi * 16 + q4 * 4 + r;
                int n = blockIdx.y * 128 + wc * 64 + ni * 16 + (lane & 15);
                out[(size_t)m * EMB + n] = acc[mi][ni][r];
            }
}

extern "C" void kernel_launch(void* const* d_in, const int* in_sizes, int n_in,
                              void* d_out, int out_size, void* d_ws, size_t ws_size,
                              hipStream_t stream) {
    const float* x  = (const float*)d_in[0];
    const float* Wq = (const float*)d_in[1];
    const float* Wk = (const float*)d_in[2];
    const float* Wv = (const float*)d_in[3];
    const float* Wo = (const float*)d_in[4];
    float* out = (float*)d_out;

    char* ws = (char*)d_ws;
    size_t off = 0;
    const size_t QKV_ELEMS = (size_t)MROWS * EMB;   // 16777216
    __half* Xh  = (__half*)(ws + off); off += QKV_ELEMS * 2;          // reused as CTX
    __half* Wqh = (__half*)(ws + off); off += (size_t)EMB * EMB * 2;
    __half* Wkh = (__half*)(ws + off); off += (size_t)EMB * EMB * 2;
    __half* Wvh = (__half*)(ws + off); off += (size_t)EMB * EMB * 2;
    __half* Woh = (__half*)(ws + off); off += (size_t)EMB * EMB * 2;
    __half* Qb  = (__half*)(ws + off); off += QKV_ELEMS * 2;
    __half* Kb  = (__half*)(ws + off); off += QKV_ELEMS * 2;
    __half* Vb  = (__half*)(ws + off); off += QKV_ELEMS * 2;
    __half* Vtb = (__half*)(ws + off); off += QKV_ELEMS * 2;
    __half* Cb  = Xh;   // X dead after gemm_qkv

    cvt_f32_f16<<<16384, 256, 0, stream>>>(x,  Xh,  4194304);
    cvt_f32_f16<<<4096,  256, 0, stream>>>(Wq, Wqh, 1048576);
    cvt_f32_f16<<<4096,  256, 0, stream>>>(Wk, Wkh, 1048576);
    cvt_f32_f16<<<4096,  256, 0, stream>>>(Wv, Wvh, 1048576);
    cvt_f32_f16<<<4096,  256, 0, stream>>>(Wo, Woh, 1048576);

    gemm_qkv<<<dim3(64, 48), 256, 0, stream>>>(Xh, Wqh, Wkh, Wvh, Qb, Kb, Vb);
    transpose_v<<<dim3(64, 64), 256, 0, stream>>>(Vb, Vtb);
    attn_kernel<<<dim3(16, 64), 256, 0, stream>>>(Qb, Kb, Vtb, Cb);
    gemm_out<<<dim3(64, 16), 256, 0, stream>>>(Cb, Woh, out);
}

// Round 4
// 800.470 us; speedup vs baseline: 1.3611x; 1.0708x over previous
//
#include <hip/hip_runtime.h>
#include <hip/hip_fp16.h>

#define EMB 2048
#define NH 16
#define HD 128
#define BATCH 4
#define SEQ 2048
#define MROWS (BATCH * SEQ)   // 8192

typedef __attribute__((ext_vector_type(8))) _Float16 f16x8;
typedef __attribute__((ext_vector_type(4))) float f32x4;

typedef __attribute__((address_space(3))) unsigned int lds_u32_t;
typedef const __attribute__((address_space(1))) unsigned int glb_u32_t;

__device__ __forceinline__ void async_copy16(void* lds, const void* g) {
    __builtin_amdgcn_global_load_lds((glb_u32_t*)g, (lds_u32_t*)lds, 16, 0, 0);
}

// ---------------- fp32 -> fp16 convert ----------------
__global__ void cvt_f32_f16(const float* __restrict__ in, __half* __restrict__ out, int n4) {
    int i = blockIdx.x * 256 + threadIdx.x;
    if (i < n4) {
        float4 v = ((const float4*)in)[i];
        __half2 a, b;
        a.x = __float2half(v.x); a.y = __float2half(v.y);
        b.x = __float2half(v.z); b.y = __float2half(v.w);
        ((__half2*)out)[2 * i]     = a;
        ((__half2*)out)[2 * i + 1] = b;
    }
}

// ---------------- shared GEMM mainloop: C(128x128) = A * B^T, K = 2048 ----------------
// BK=64 halfs (128B rows = 8 x 16B chunks). T2 XOR swizzle chunk^=(row&7):
// applied on the global SOURCE address (global_load_lds writes LDS linearly,
// wave-uniform base + lane*16) and on the ds_read side. Round-3 profile:
// [128][32] layout had 8-way conflicts on every b128 frag read
// (SQ_LDS_BANK_CONFLICT 2.5e7, MfmaUtil 26.6%). Swizzled: 16 lanes spread
// over 8 bank-quads = 2-way = free. BK=64 also halves barrier count.
__device__ __forceinline__ void gemm_mainloop(const __half* __restrict__ A,
                                              const __half* __restrict__ B,
                                              int m0, int n0,
                                              short* sA, short* sB,
                                              f32x4 acc[4][4]) {
    const int tid  = threadIdx.x;
    const int wave = tid >> 6;
    const int lane = tid & 63;
    const int wr = wave >> 1, wc = wave & 1;
    const int frow = lane & 15;
    const int q4   = lane >> 4;          // 0..3 = 16B chunk within a 32-half K-slice
    const int r0 = tid >> 3;             // 0..31 row within a 32-row issue
    const int cs = ((tid & 7) ^ (r0 & 7)) * 16;   // pre-swizzled source chunk (bytes)
    const char* gA = (const char*)A;
    const char* gB = (const char*)B;
    char* lA = (char*)sA;
    char* lB = (char*)sB;
    const int wbase = wave * 1024;

    for (int kt = 0; kt < EMB; kt += 64) {
        size_t kb = (size_t)kt * 2;
#pragma unroll
        for (int j = 0; j < 4; j++) {
            int r = j * 32 + r0;
            async_copy16(lA + j * 4096 + wbase,
                         gA + ((size_t)(m0 + r) * EMB) * 2 + kb + cs);
        }
#pragma unroll
        for (int j = 0; j < 4; j++) {
            int r = j * 32 + r0;
            async_copy16(lB + j * 4096 + wbase,
                         gB + ((size_t)(n0 + r) * EMB) * 2 + kb + cs);
        }
        __syncthreads();

#pragma unroll
        for (int ks = 0; ks < 2; ks++) {
            f16x8 af[4], bf[4];
            const int cxa = (ks * 4 + q4);
#pragma unroll
            for (int i = 0; i < 4; i++)
                af[i] = *(const f16x8*)&sA[(wr * 64 + i * 16 + frow) * 64 + ((cxa ^ (frow & 7)) * 8)];
#pragma unroll
            for (int i = 0; i < 4; i++)
                bf[i] = *(const f16x8*)&sB[(wc * 64 + i * 16 + frow) * 64 + ((cxa ^ (frow & 7)) * 8)];
#pragma unroll
            for (int mi = 0; mi < 4; mi++)
#pragma unroll
                for (int ni = 0; ni < 4; ni++)
                    acc[mi][ni] = __builtin_amdgcn_mfma_f32_16x16x32_f16(af[mi], bf[ni], acc[mi][ni], 0, 0, 0);
        }
        __syncthreads();
    }
}

// ---------------- QKV projection + RoPE, writes (B,H,S,D) fp16 ----------------
__global__ __launch_bounds__(256) void gemm_qkv(const __half* __restrict__ X,
                                                const __half* __restrict__ Wq,
                                                const __half* __restrict__ Wk,
                                                const __half* __restrict__ Wv,
                                                __half* __restrict__ Q,
                                                __half* __restrict__ K,
                                                __half* __restrict__ V) {
    __shared__ short sA[128 * 64];
    __shared__ short sB[128 * 64];
    const int mblk = blockIdx.x;
    const int nb   = blockIdx.y;
    const int wsel = nb >> 4;
    const int nloc = (nb & 15) * 128;
    const __half* W = (wsel == 0) ? Wq : ((wsel == 1) ? Wk : Wv);

    f32x4 z = {0.f, 0.f, 0.f, 0.f};
    f32x4 acc[4][4];
#pragma unroll
    for (int i = 0; i < 4; i++)
#pragma unroll
        for (int j = 0; j < 4; j++) acc[i][j] = z;

    gemm_mainloop(X, W, mblk * 128, nloc, sA, sB, acc);

    const int lane = threadIdx.x & 63;
    const int wave = threadIdx.x >> 6;
    const int wr = wave >> 1, wc = wave & 1;
    const int q4 = lane >> 4;
    __half* Obuf = (wsel == 0) ? Q : ((wsel == 1) ? K : V);
    const bool rope = (wsel < 2);

#pragma unroll
    for (int ni = 0; ni < 4; ni++) {
        int n = nloc + wc * 64 + ni * 16 + (lane & 15);
        int h = n >> 7, d = n & 127;
        float invf = rope ? __expf(-((float)(d & ~1)) * (9.210340371976184f / 128.0f)) : 0.f;
#pragma unroll
        for (int mi = 0; mi < 4; mi++) {
#pragma unroll
            for (int r = 0; r < 4; r++) {
                int m = mblk * 128 + wr * 64 + mi * 16 + q4 * 4 + r;
                int b = m >> 11, s = m & 2047;
                float v = acc[mi][ni][r];
                float res;
                if (rope) {
                    float p = __shfl_xor(v, 1);
                    float ang = (float)s * invf;
                    float sn, cs;
                    __sincosf(ang, &sn, &cs);
                    if ((lane & 1) == 0) res = v * cs - p * sn;
                    else                 res = v * cs + p * sn;
                } else {
                    res = v;
                }
                float pr = __shfl_xor(res, 1);
                if ((lane & 1) == 0) {
                    __half2 hv;
                    hv.x = __float2half(res);
                    hv.y = __float2half(pr);
                    size_t off = ((size_t)(b * NH + h) * SEQ + s) * HD + d;
                    *(__half2*)(Obuf + off) = hv;
                }
            }
        }
    }
}

// ---------------- V transpose: V[bh][s][d] -> Vt[bh][d][s] ----------------
__global__ __launch_bounds__(256) void transpose_v(const __half* __restrict__ V,
                                                   __half* __restrict__ Vt) {
    __shared__ short t[64 * 65];
    const int st = blockIdx.x & 31;
    const int dt = (blockIdx.x >> 5) & 1;
    const int bh = blockIdx.y;
    const int tid = threadIdx.x;
    const __half* Vh = V + (size_t)bh * SEQ * HD;
    __half* Vo = Vt + (size_t)bh * SEQ * HD;
#pragma unroll
    for (int k = 0; k < 2; k++) {
        int id = k * 256 + tid;
        int r = id >> 3, c8 = id & 7;
        f16x8 v = *(const f16x8*)(Vh + (size_t)(st * 64 + r) * HD + dt * 64 + c8 * 8);
#pragma unroll
        for (int e = 0; e < 8; e++) t[r * 65 + c8 * 8 + e] = ((short*)&v)[e];
    }
    __syncthreads();
#pragma unroll
    for (int k = 0; k < 2; k++) {
        int id = k * 256 + tid;
        int dr = id >> 3, sc8 = id & 7;
        f16x8 v;
#pragma unroll
        for (int e = 0; e < 8; e++) ((short*)&v)[e] = t[(sc8 * 8 + e) * 65 + dr];
        *(f16x8*)(Vo + (size_t)(dt * 64 + dr) * SEQ + st * 64 + sc8 * 8) = v;
    }
}

// ---------------- causal flash attention v5 ----------------
// BQ=64 (16 rows/wave), BK=64. LDS 40KB: sK 16KB + sV 16KB + sP 8KB.
// Pair-balanced grid: 1024 blocks, each handles q-tiles (31-x) then (x)
// = exactly 33 K-tile iterations -> uniform blocks, no drain tail.
// launch_bounds(256,3): (256,4) forced VGPR 84->64 and spilled. (256,3)
// keeps ~84 VGPR; 84 <= 128 so HW still fits 4 blocks/CU (LDS exact fit).
// XCD swizzle: dispatch-id % 8 -> XCD; each XCD owns 8 exclusive heads.
__global__ __launch_bounds__(256, 3) void attn_kernel(const __half* __restrict__ Q,
                                                      const __half* __restrict__ K,
                                                      const __half* __restrict__ Vt,
                                                      __half* __restrict__ CTX) {
    __shared__ short sK[64 * 128];      // K tile: 64 keys x 128 d, 16-chunk swizzle
    __shared__ short sV[128 * 64];      // V^T tile: 128 d x 64 keys, 8-chunk swizzle
    __shared__ short sP[4][16 * 64];    // per-wave P scratch
    const int disp  = blockIdx.y * 16 + blockIdx.x;   // 0..1023, dispatch order
    const int wid   = (disp & 7) * 128 + (disp >> 3); // bijective, nwg%8==0
    const int pairx = wid & 15;                       // 0..15
    const int bh    = wid >> 4;                       // 0..63
    const int b = bh >> 4, h = bh & 15;
    const int tid = threadIdx.x;
    const int wave = tid >> 6, lane = tid & 63;
    const int fr = lane & 15, q4 = lane >> 4;
    const size_t headoff = (size_t)bh * SEQ * HD;
    const __half* Qh = Q + headoff;
    const __half* Kh = K + headoff;
    const __half* Vth = Vt + headoff;   // [d][s]
    short* sPw = &sP[wave][0];

    f32x4 z = {0.f, 0.f, 0.f, 0.f};

#pragma unroll 1
    for (int pass = 0; pass < 2; pass++) {
        const int qt = pass ? pairx : (31 - pairx);   // heavy tile first
        const int nk = qt + 1;

        // Q fragments (wave rows qt*64 + wave*16 + fr), scale folded
        f16x8 qf[4];
#pragma unroll
        for (int ds = 0; ds < 4; ds++) {
            qf[ds] = *(const f16x8*)(Qh + (size_t)(qt * 64 + wave * 16 + fr) * HD + ds * 32 + q4 * 8);
            qf[ds] = qf[ds] * (_Float16)0.08838834764831845f;
        }

        f32x4 accO[8];
#pragma unroll
        for (int i = 0; i < 8; i++) accO[i] = z;
        float mrow[4], lrow[4];
#pragma unroll
        for (int r = 0; r < 4; r++) { mrow[r] = -INFINITY; lrow[r] = 0.f; }

        // prefetch registers (tile 0)
        f16x8 kpre[4], vpre[4];
#pragma unroll
        for (int j = 0; j < 4; j++) {
            int id = j * 256 + tid;
            int row = id >> 4, c = id & 15;
            kpre[j] = *(const f16x8*)(Kh + (size_t)row * HD + c * 8);
        }
#pragma unroll
        for (int j = 0; j < 4; j++) {
            int id = j * 256 + tid;
            int d = id >> 3, c = id & 7;
            vpre[j] = *(const f16x8*)(Vth + (size_t)d * SEQ + c * 8);
        }

        for (int kt = 0; kt < nk; kt++) {
            __syncthreads();   // barrier A: previous compute done reading sK/sV
            // ---- VGPR -> LDS (swizzled) ----
#pragma unroll
            for (int j = 0; j < 4; j++) {
                int id = j * 256 + tid;
                int row = id >> 4, c = id & 15;
                *(f16x8*)&sK[row * 128 + ((c ^ (row & 15)) * 8)] = kpre[j];
            }
#pragma unroll
            for (int j = 0; j < 4; j++) {
                int id = j * 256 + tid;
                int d = id >> 3, c = id & 7;
                *(f16x8*)&sV[d * 64 + ((c ^ (d & 7)) * 8)] = vpre[j];
            }
            __syncthreads();   // barrier B: tiles visible

            // ---- issue next tile's global loads (overlap with compute) ----
            if (kt + 1 < nk) {
                int kbase = (kt + 1) * 64;
#pragma unroll
                for (int j = 0; j < 4; j++) {
                    int id = j * 256 + tid;
                    int row = id >> 4, c = id & 15;
                    kpre[j] = *(const f16x8*)(Kh + (size_t)(kbase + row) * HD + c * 8);
                }
#pragma unroll
                for (int j = 0; j < 4; j++) {
                    int id = j * 256 + tid;
                    int d = id >> 3, c = id & 7;
                    vpre[j] = *(const f16x8*)(Vth + (size_t)d * SEQ + kbase + c * 8);
                }
            }

            // ---- S = Q K^T (16 rows x 64 cols per wave) ----
            f32x4 accS[4];
#pragma unroll
            for (int i = 0; i < 4; i++) accS[i] = z;
            __builtin_amdgcn_s_setprio(1);
#pragma unroll
            for (int ds = 0; ds < 4; ds++) {
                f16x8 kf[4];
#pragma unroll
                for (int ni = 0; ni < 4; ni++)
                    kf[ni] = *(const f16x8*)&sK[(ni * 16 + fr) * 128 + (((ds * 4 + q4) ^ fr) * 8)];
#pragma unroll
                for (int ni = 0; ni < 4; ni++)
                    accS[ni] = __builtin_amdgcn_mfma_f32_16x16x32_f16(qf[ds], kf[ni], accS[ni], 0, 0, 0);
            }
            __builtin_amdgcn_s_setprio(0);

            // ---- causal mask (diagonal tile only) ----
            if (kt == qt) {
#pragma unroll
                for (int ni = 0; ni < 4; ni++) {
                    int kcol = ni * 16 + fr;
#pragma unroll
                    for (int r = 0; r < 4; r++) {
                        int qrow = wave * 16 + q4 * 4 + r;
                        if (kcol > qrow) accS[ni][r] = -INFINITY;
                    }
                }
            }

            // ---- online softmax ----
#pragma unroll
            for (int r = 0; r < 4; r++) {
                float mold = mrow[r];
                float mx = mold;
#pragma unroll
                for (int ni = 0; ni < 4; ni++) mx = fmaxf(mx, accS[ni][r]);
#pragma unroll
                for (int off = 1; off < 16; off <<= 1)
                    mx = fmaxf(mx, __shfl_xor(mx, off));
                float alpha = __expf(mold - mx);
                mrow[r] = mx;
                float rs = 0.f;
#pragma unroll
                for (int ni = 0; ni < 4; ni++) {
                    float p = __expf(accS[ni][r] - mx);
                    rs += p;
                    accS[ni][r] = p;
                }
#pragma unroll
                for (int off = 1; off < 16; off <<= 1)
                    rs += __shfl_xor(rs, off);
                lrow[r] = lrow[r] * alpha + rs;
#pragma unroll
                for (int di = 0; di < 8; di++)
                    accO[di][r] *= alpha;
            }

            // ---- P -> wave-private scratch (no barrier; intra-wave ordering) ----
#pragma unroll
            for (int ni = 0; ni < 4; ni++)
#pragma unroll
                for (int r = 0; r < 4; r++) {
                    float p = accS[ni][r];
                    float pp = __shfl_xor(p, 1);
                    if ((lane & 1) == 0) {
                        int row = q4 * 4 + r;
                        int col = ni * 16 + fr;                 // even
                        int xc = (col >> 3) ^ (row & 7);
                        __half2 h2;
                        h2.x = __float2half(p);
                        h2.y = __float2half(pp);
                        *(__half2*)&sPw[row * 64 + xc * 8 + (col & 7)] = h2;
                    }
                }

            // ---- O += P V ----
            __builtin_amdgcn_s_setprio(1);
#pragma unroll
            for (int ns = 0; ns < 2; ns++) {
                f16x8 pf = *(const f16x8*)&sPw[fr * 64 + (((ns * 4 + q4) ^ (fr & 7)) * 8)];
#pragma unroll
                for (int di = 0; di < 8; di++) {
                    f16x8 vf = *(const f16x8*)&sV[(di * 16 + fr) * 64 + (((ns * 4 + q4) ^ (fr & 7)) * 8)];
                    accO[di] = __builtin_amdgcn_mfma_f32_16x16x32_f16(pf, vf, accO[di], 0, 0, 0);
                }
            }
            __builtin_amdgcn_s_setprio(0);
            // no barrier here: next iteration's barrier A protects sK/sV
        }

        // ---- epilogue ----
        float linv[4];
#pragma unroll
        for (int r = 0; r < 4; r++) linv[r] = 1.f / lrow[r];

#pragma unroll
        for (int di = 0; di < 8; di++)
#pragma unroll
            for (int r = 0; r < 4; r++) {
                float o = accO[di][r] * linv[r];
                float po = __shfl_xor(o, 1);
                if ((lane & 1) == 0) {
                    int srow = qt * 64 + wave * 16 + q4 * 4 + r;
                    int d = di * 16 + fr;  // even
                    size_t off = ((size_t)(b * SEQ + srow)) * EMB + h * HD + d;
                    __half2 h2;
                    h2.x = __float2half(o);
                    h2.y = __float2half(po);
                    *(__half2*)&CTX[off] = h2;
                }
            }
    }
}

// ---------------- output projection: out(fp32) = CTX * Wo^T ----------------
__global__ __launch_bounds__(256) void gemm_out(const __half* __restrict__ CTX,
                                                const __half* __restrict__ Wo,
                                                float* __restrict__ out) {
    __shared__ short sA[128 * 64];
    __shared__ short sB[128 * 64];
    f32x4 z = {0.f, 0.f, 0.f, 0.f};
    f32x4 acc[4][4];
#pragma unroll
    for (int i = 0; i < 4; i++)
#pragma unroll
        for (int j = 0; j < 4; j++) acc[i][j] = z;

    gemm_mainloop(CTX, Wo, blockIdx.x * 128, blockIdx.y * 128, sA, sB, acc);

    const int lane = threadIdx.x & 63;
    const int wave = threadIdx.x >> 6;
    const int wr = wave >> 1, wc = wave & 1;
    const int q4 = lane >> 4;
#pragma unroll
    for (int mi = 0; mi < 4; mi++)
#pragma unroll
        for (int ni = 0; ni < 4; ni++)
#pragma unroll
            for (int r = 0; r < 4; r++) {
                int m = blockIdx.x * 128 + wr * 64 + mi * 16 + q4 * 4 + r;
                int n = blockIdx.y * 128 + wc * 64 + ni * 16 + (lane & 15);
                out[(size_t)m * EMB + n] = acc[mi][ni][r];
            }
}

extern "C" void kernel_launch(void* const* d_in, const int* in_sizes, int n_in,
                              void* d_out, int out_size, void* d_ws, size_t ws_size,
                              hipStream_t stream) {
    const float* x  = (const float*)d_in[0];
    const float* Wq = (const float*)d_in[1];
    const float* Wk = (const float*)d_in[2];
    const float* Wv = (const float*)d_in[3];
    const float* Wo = (const float*)d_in[4];
    float* out = (float*)d_out;

    char* ws = (char*)d_ws;
    size_t off = 0;
    const size_t QKV_ELEMS = (size_t)MROWS * EMB;   // 16777216
    __half* Xh  = (__half*)(ws + off); off += QKV_ELEMS * 2;          // reused as CTX
    __half* Wqh = (__half*)(ws + off); off += (size_t)EMB * EMB * 2;
    __half* Wkh = (__half*)(ws + off); off += (size_t)EMB * EMB * 2;
    __half* Wvh = (__half*)(ws + off); off += (size_t)EMB * EMB * 2;
    __half* Woh = (__half*)(ws + off); off += (size_t)EMB * EMB * 2;
    __half* Qb  = (__half*)(ws + off); off += QKV_ELEMS * 2;
    __half* Kb  = (__half*)(ws + off); off += QKV_ELEMS * 2;
    __half* Vb  = (__half*)(ws + off); off += QKV_ELEMS * 2;
    __half* Vtb = (__half*)(ws + off); off += QKV_ELEMS * 2;
    __half* Cb  = Xh;   // X dead after gemm_qkv

    cvt_f32_f16<<<16384, 256, 0, stream>>>(x,  Xh,  4194304);
    cvt_f32_f16<<<4096,  256, 0, stream>>>(Wq, Wqh, 1048576);
    cvt_f32_f16<<<4096,  256, 0, stream>>>(Wk, Wkh, 1048576);
    cvt_f32_f16<<<4096,  256, 0, stream>>>(Wv, Wvh, 1048576);
    cvt_f32_f16<<<4096,  256, 0, stream>>>(Wo, Woh, 1048576);

    gemm_qkv<<<dim3(64, 48), 256, 0, stream>>>(Xh, Wqh, Wkh, Wvh, Qb, Kb, Vb);
    transpose_v<<<dim3(64, 64), 256, 0, stream>>>(Vb, Vtb);
    attn_kernel<<<dim3(16, 64), 256, 0, stream>>>(Qb, Kb, Vtb, Cb);
    gemm_out<<<dim3(64, 16), 256, 0, stream>>>(Cb, Woh, out);
}

// Round 5
// 777.133 us; speedup vs baseline: 1.4020x; 1.0300x over previous
//
#include <hip/hip_runtime.h>
#include <hip/hip_fp16.h>

#define EMB 2048
#define NH 16
#define HD 128
#define BATCH 4
#define SEQ 2048
#define MROWS (BATCH * SEQ)   // 8192

typedef __attribute__((ext_vector_type(8))) _Float16 f16x8;
typedef __attribute__((ext_vector_type(4))) _Float16 f16x4;
typedef __attribute__((ext_vector_type(4))) float f32x4;

typedef __attribute__((address_space(3))) unsigned int lds_u32_t;
typedef const __attribute__((address_space(1))) unsigned int glb_u32_t;

__device__ __forceinline__ void async_copy16(void* lds, const void* g) {
    __builtin_amdgcn_global_load_lds((glb_u32_t*)g, (lds_u32_t*)lds, 16, 0, 0);
}

// ---------------- fused fp32 -> fp16 convert (all 5 tensors, one launch) ----------------
// x: 16384 blocks (4194304 float4), each weight: 4096 blocks (1048576 float4). Exact fit.
__global__ void cvt_all(const float* __restrict__ x,  const float* __restrict__ wq,
                        const float* __restrict__ wk, const float* __restrict__ wv,
                        const float* __restrict__ wo,
                        __half* __restrict__ xh,  __half* __restrict__ wqh,
                        __half* __restrict__ wkh, __half* __restrict__ wvh,
                        __half* __restrict__ woh) {
    int bid = blockIdx.x;
    const float* s;
    __half* d;
    int idx;
    if (bid < 16384) {
        s = x; d = xh; idx = bid * 256 + threadIdx.x;
    } else {
        int b2 = bid - 16384;
        int w = b2 >> 12;
        s = (w == 0) ? wq : (w == 1) ? wk : (w == 2) ? wv : wo;
        d = (w == 0) ? wqh : (w == 1) ? wkh : (w == 2) ? wvh : woh;
        idx = (b2 & 4095) * 256 + threadIdx.x;
    }
    float4 v = ((const float4*)s)[idx];
    __half2 a, b;
    a.x = __float2half(v.x); a.y = __float2half(v.y);
    b.x = __float2half(v.z); b.y = __float2half(v.w);
    ((__half2*)d)[2 * idx]     = a;
    ((__half2*)d)[2 * idx + 1] = b;
}

// ---------------- pipelined GEMM mainloop: C(128x128) = A * B^T, K = 2048 ----------------
// Round-4 post-mortem: conflicts 0 but MfmaUtil stuck at 30.5% -> the 2-barrier
// stage/syncthreads/compute/syncthreads structure serializes global-load latency
// (syncthreads drains vmcnt(0)). This version: BK=32, THREE LDS buffers (48KB),
// depth-2 prefetch, counted vmcnt + raw s_barrier (loads stay in flight across
// the barrier). Per K-tile: vmcnt(4) -> barrier -> compute buf[t%3] -> STAGE(t+2).
// Swizzle (T2 both-sides): stored chunk c holds global chunk c^(row&3); read at
// slot q4^(frow&3) -> uniform 8 lanes/bank-quad, conflict-free (round-4 verified
// scheme, re-derived for 4-chunk rows).
__device__ __forceinline__ void gemm_mainloop(const __half* __restrict__ A,
                                              const __half* __restrict__ B,
                                              int m0, int n0,
                                              short* sA, short* sB,   // each [3][128*32]
                                              f32x4 acc[4][4]) {
    const int tid  = threadIdx.x;
    const int wave = tid >> 6;
    const int lane = tid & 63;
    const int wr = wave >> 1, wc = wave & 1;
    const int frow = lane & 15;
    const int q4   = lane >> 4;                 // k-chunk 0..3 (8 halfs each)
    const int r0   = tid >> 2;                  // 0..63: staging row within 64-row group
    const int csw  = ((tid & 3) ^ (r0 & 3)) * 16;  // pre-swizzled source chunk (bytes)
    const char* gA = (const char*)A + (size_t)(m0 + r0) * (EMB * 2) + csw;
    const char* gB = (const char*)B + (size_t)(n0 + r0) * (EMB * 2) + csw;
    const size_t rstep = (size_t)64 * EMB * 2;  // +64 rows
    char* lA = (char*)sA;
    char* lB = (char*)sB;
    const int ldst = tid * 16;                  // linear LDS dest (uniform + lane*16)

#define STAGE_TILE(t, b) do {                                          \
        size_t ko = (size_t)(t) * 64;                                  \
        async_copy16(lA + (b) * 8192 + ldst,        gA + ko);          \
        async_copy16(lA + (b) * 8192 + 4096 + ldst, gA + rstep + ko);  \
        async_copy16(lB + (b) * 8192 + ldst,        gB + ko);          \
        async_copy16(lB + (b) * 8192 + 4096 + ldst, gB + rstep + ko);  \
    } while (0)

    const int nt = EMB / 32;   // 64 K-tiles
    STAGE_TILE(0, 0);
    STAGE_TILE(1, 1);

    int cb = 0;
    for (int t = 0; t < nt; ++t) {
        // tile t's 4 loads are the oldest; keep newest 4 (tile t+1) in flight
        if (t < nt - 1) asm volatile("s_waitcnt vmcnt(4)" ::: "memory");
        else            asm volatile("s_waitcnt vmcnt(0)" ::: "memory");
        asm volatile("" ::: "memory");
        __builtin_amdgcn_s_barrier();
        asm volatile("" ::: "memory");

        const short* bufA = sA + cb * 4096;
        const short* bufB = sB + cb * 4096;
        f16x8 af[4], bf[4];
        const int slot = (q4 ^ (frow & 3)) * 8;
#pragma unroll
        for (int i = 0; i < 4; i++)
            af[i] = *(const f16x8*)&bufA[(wr * 64 + i * 16 + frow) * 32 + slot];
#pragma unroll
        for (int i = 0; i < 4; i++)
            bf[i] = *(const f16x8*)&bufB[(wc * 64 + i * 16 + frow) * 32 + slot];
#pragma unroll
        for (int mi = 0; mi < 4; mi++)
#pragma unroll
            for (int ni = 0; ni < 4; ni++)
                acc[mi][ni] = __builtin_amdgcn_mfma_f32_16x16x32_f16(af[mi], bf[ni], acc[mi][ni], 0, 0, 0);

        // issue tile t+2 into the buffer last read at iteration t-1 (all waves
        // passed this iteration's barrier => done reading it)
        if (t + 2 < nt) {
            int sb = cb + 2; if (sb >= 3) sb -= 3;
            STAGE_TILE(t + 2, sb);
        }
        cb = (cb == 2) ? 0 : cb + 1;
    }
#undef STAGE_TILE
}

// ---------------- QKV projection + RoPE; Q,K -> (B,H,S,D), V -> (B,H,D,S) ----------------
__global__ __launch_bounds__(256) void gemm_qkv(const __half* __restrict__ X,
                                                const __half* __restrict__ Wq,
                                                const __half* __restrict__ Wk,
                                                const __half* __restrict__ Wv,
                                                __half* __restrict__ Q,
                                                __half* __restrict__ K,
                                                __half* __restrict__ Vt) {
    __shared__ short sA[3 * 128 * 32];
    __shared__ short sB[3 * 128 * 32];
    const int mblk = blockIdx.x;
    const int nb   = blockIdx.y;
    const int wsel = nb >> 4;
    const int nloc = (nb & 15) * 128;
    const __half* W = (wsel == 0) ? Wq : ((wsel == 1) ? Wk : Wv);

    f32x4 z = {0.f, 0.f, 0.f, 0.f};
    f32x4 acc[4][4];
#pragma unroll
    for (int i = 0; i < 4; i++)
#pragma unroll
        for (int j = 0; j < 4; j++) acc[i][j] = z;

    gemm_mainloop(X, W, mblk * 128, nloc, sA, sB, acc);

    const int lane = threadIdx.x & 63;
    const int wave = threadIdx.x >> 6;
    const int wr = wave >> 1, wc = wave & 1;
    const int q4 = lane >> 4;

    if (wsel == 2) {
        // V: write transposed directly, Vt[bh][d][s]. Lane's 4 r-values are 4
        // consecutive s -> one 8B store, no shuffles. Kills transpose_v kernel.
#pragma unroll
        for (int ni = 0; ni < 4; ni++) {
            int n = nloc + wc * 64 + ni * 16 + (lane & 15);
            int h = n >> 7, d = n & 127;
#pragma unroll
            for (int mi = 0; mi < 4; mi++) {
                int m = mblk * 128 + wr * 64 + mi * 16 + q4 * 4;
                int b = m >> 11, s = m & 2047;
                f16x4 hv;
#pragma unroll
                for (int r = 0; r < 4; r++) hv[r] = (_Float16)acc[mi][ni][r];
                *(f16x4*)(Vt + ((size_t)(b * NH + h) * HD + d) * SEQ + s) = hv;
            }
        }
        return;
    }

    __half* Obuf = (wsel == 0) ? Q : K;
#pragma unroll
    for (int ni = 0; ni < 4; ni++) {
        int n = nloc + wc * 64 + ni * 16 + (lane & 15);
        int h = n >> 7, d = n & 127;
        float invf = __expf(-((float)(d & ~1)) * (9.210340371976184f / 128.0f));
#pragma unroll
        for (int mi = 0; mi < 4; mi++) {
#pragma unroll
            for (int r = 0; r < 4; r++) {
                int m = mblk * 128 + wr * 64 + mi * 16 + q4 * 4 + r;
                int b = m >> 11, s = m & 2047;
                float v = acc[mi][ni][r];
                float p = __shfl_xor(v, 1);
                float ang = (float)s * invf;
                float sn, cs;
                __sincosf(ang, &sn, &cs);
                float res;
                if ((lane & 1) == 0) res = v * cs - p * sn;
                else                 res = v * cs + p * sn;
                float pr = __shfl_xor(res, 1);
                if ((lane & 1) == 0) {
                    __half2 hv;
                    hv.x = __float2half(res);
                    hv.y = __float2half(pr);
                    size_t off = ((size_t)(b * NH + h) * SEQ + s) * HD + d;
                    *(__half2*)(Obuf + off) = hv;
                }
            }
        }
    }
}

// ---------------- causal flash attention v5 (unchanged from round 4) ----------------
// BQ=64 (16 rows/wave), BK=64. LDS 40KB. Pair-balanced grid (33 iters/block),
// launch_bounds(256,3) (no spill, HW fits 4 blocks/CU), XCD-aware head mapping.
__global__ __launch_bounds__(256, 3) void attn_kernel(const __half* __restrict__ Q,
                                                      const __half* __restrict__ K,
                                                      const __half* __restrict__ Vt,
                                                      __half* __restrict__ CTX) {
    __shared__ short sK[64 * 128];      // K tile: 64 keys x 128 d, 16-chunk swizzle
    __shared__ short sV[128 * 64];      // V^T tile: 128 d x 64 keys, 8-chunk swizzle
    __shared__ short sP[4][16 * 64];    // per-wave P scratch
    const int disp  = blockIdx.y * 16 + blockIdx.x;   // 0..1023, dispatch order
    const int wid   = (disp & 7) * 128 + (disp >> 3); // bijective, nwg%8==0
    const int pairx = wid & 15;                       // 0..15
    const int bh    = wid >> 4;                       // 0..63
    const int b = bh >> 4, h = bh & 15;
    const int tid = threadIdx.x;
    const int wave = tid >> 6, lane = tid & 63;
    const int fr = lane & 15, q4 = lane >> 4;
    const size_t headoff = (size_t)bh * SEQ * HD;
    const __half* Qh = Q + headoff;
    const __half* Kh = K + headoff;
    const __half* Vth = Vt + headoff;   // [d][s]
    short* sPw = &sP[wave][0];

    f32x4 z = {0.f, 0.f, 0.f, 0.f};

#pragma unroll 1
    for (int pass = 0; pass < 2; pass++) {
        const int qt = pass ? pairx : (31 - pairx);   // heavy tile first
        const int nk = qt + 1;

        // Q fragments (wave rows qt*64 + wave*16 + fr), scale folded
        f16x8 qf[4];
#pragma unroll
        for (int ds = 0; ds < 4; ds++) {
            qf[ds] = *(const f16x8*)(Qh + (size_t)(qt * 64 + wave * 16 + fr) * HD + ds * 32 + q4 * 8);
            qf[ds] = qf[ds] * (_Float16)0.08838834764831845f;
        }

        f32x4 accO[8];
#pragma unroll
        for (int i = 0; i < 8; i++) accO[i] = z;
        float mrow[4], lrow[4];
#pragma unroll
        for (int r = 0; r < 4; r++) { mrow[r] = -INFINITY; lrow[r] = 0.f; }

        // prefetch registers (tile 0)
        f16x8 kpre[4], vpre[4];
#pragma unroll
        for (int j = 0; j < 4; j++) {
            int id = j * 256 + tid;
            int row = id >> 4, c = id & 15;
            kpre[j] = *(const f16x8*)(Kh + (size_t)row * HD + c * 8);
        }
#pragma unroll
        for (int j = 0; j < 4; j++) {
            int id = j * 256 + tid;
            int d = id >> 3, c = id & 7;
            vpre[j] = *(const f16x8*)(Vth + (size_t)d * SEQ + c * 8);
        }

        for (int kt = 0; kt < nk; kt++) {
            __syncthreads();   // barrier A: previous compute done reading sK/sV
            // ---- VGPR -> LDS (swizzled) ----
#pragma unroll
            for (int j = 0; j < 4; j++) {
                int id = j * 256 + tid;
                int row = id >> 4, c = id & 15;
                *(f16x8*)&sK[row * 128 + ((c ^ (row & 15)) * 8)] = kpre[j];
            }
#pragma unroll
            for (int j = 0; j < 4; j++) {
                int id = j * 256 + tid;
                int d = id >> 3, c = id & 7;
                *(f16x8*)&sV[d * 64 + ((c ^ (d & 7)) * 8)] = vpre[j];
            }
            __syncthreads();   // barrier B: tiles visible

            // ---- issue next tile's global loads (overlap with compute) ----
            if (kt + 1 < nk) {
                int kbase = (kt + 1) * 64;
#pragma unroll
                for (int j = 0; j < 4; j++) {
                    int id = j * 256 + tid;
                    int row = id >> 4, c = id & 15;
                    kpre[j] = *(const f16x8*)(Kh + (size_t)(kbase + row) * HD + c * 8);
                }
#pragma unroll
                for (int j = 0; j < 4; j++) {
                    int id = j * 256 + tid;
                    int d = id >> 3, c = id & 7;
                    vpre[j] = *(const f16x8*)(Vth + (size_t)d * SEQ + kbase + c * 8);
                }
            }

            // ---- S = Q K^T (16 rows x 64 cols per wave) ----
            f32x4 accS[4];
#pragma unroll
            for (int i = 0; i < 4; i++) accS[i] = z;
            __builtin_amdgcn_s_setprio(1);
#pragma unroll
            for (int ds = 0; ds < 4; ds++) {
                f16x8 kf[4];
#pragma unroll
                for (int ni = 0; ni < 4; ni++)
                    kf[ni] = *(const f16x8*)&sK[(ni * 16 + fr) * 128 + (((ds * 4 + q4) ^ fr) * 8)];
#pragma unroll
                for (int ni = 0; ni < 4; ni++)
                    accS[ni] = __builtin_amdgcn_mfma_f32_16x16x32_f16(qf[ds], kf[ni], accS[ni], 0, 0, 0);
            }
            __builtin_amdgcn_s_setprio(0);

            // ---- causal mask (diagonal tile only) ----
            if (kt == qt) {
#pragma unroll
                for (int ni = 0; ni < 4; ni++) {
                    int kcol = ni * 16 + fr;
#pragma unroll
                    for (int r = 0; r < 4; r++) {
                        int qrow = wave * 16 + q4 * 4 + r;
                        if (kcol > qrow) accS[ni][r] = -INFINITY;
                    }
                }
            }

            // ---- online softmax ----
#pragma unroll
            for (int r = 0; r < 4; r++) {
                float mold = mrow[r];
                float mx = mold;
#pragma unroll
                for (int ni = 0; ni < 4; ni++) mx = fmaxf(mx, accS[ni][r]);
#pragma unroll
                for (int off = 1; off < 16; off <<= 1)
                    mx = fmaxf(mx, __shfl_xor(mx, off));
                float alpha = __expf(mold - mx);
                mrow[r] = mx;
                float rs = 0.f;
#pragma unroll
                for (int ni = 0; ni < 4; ni++) {
                    float p = __expf(accS[ni][r] - mx);
                    rs += p;
                    accS[ni][r] = p;
                }
#pragma unroll
                for (int off = 1; off < 16; off <<= 1)
                    rs += __shfl_xor(rs, off);
                lrow[r] = lrow[r] * alpha + rs;
#pragma unroll
                for (int di = 0; di < 8; di++)
                    accO[di][r] *= alpha;
            }

            // ---- P -> wave-private scratch (no barrier; intra-wave ordering) ----
#pragma unroll
            for (int ni = 0; ni < 4; ni++)
#pragma unroll
                for (int r = 0; r < 4; r++) {
                    float p = accS[ni][r];
                    float pp = __shfl_xor(p, 1);
                    if ((lane & 1) == 0) {
                        int row = q4 * 4 + r;
                        int col = ni * 16 + fr;                 // even
                        int xc = (col >> 3) ^ (row & 7);
                        __half2 h2;
                        h2.x = __float2half(p);
                        h2.y = __float2half(pp);
                        *(__half2*)&sPw[row * 64 + xc * 8 + (col & 7)] = h2;
                    }
                }

            // ---- O += P V ----
            __builtin_amdgcn_s_setprio(1);
#pragma unroll
            for (int ns = 0; ns < 2; ns++) {
                f16x8 pf = *(const f16x8*)&sPw[fr * 64 + (((ns * 4 + q4) ^ (fr & 7)) * 8)];
#pragma unroll
                for (int di = 0; di < 8; di++) {
                    f16x8 vf = *(const f16x8*)&sV[(di * 16 + fr) * 64 + (((ns * 4 + q4) ^ (fr & 7)) * 8)];
                    accO[di] = __builtin_amdgcn_mfma_f32_16x16x32_f16(pf, vf, accO[di], 0, 0, 0);
                }
            }
            __builtin_amdgcn_s_setprio(0);
            // no barrier here: next iteration's barrier A protects sK/sV
        }

        // ---- epilogue ----
        float linv[4];
#pragma unroll
        for (int r = 0; r < 4; r++) linv[r] = 1.f / lrow[r];

#pragma unroll
        for (int di = 0; di < 8; di++)
#pragma unroll
            for (int r = 0; r < 4; r++) {
                float o = accO[di][r] * linv[r];
                float po = __shfl_xor(o, 1);
                if ((lane & 1) == 0) {
                    int srow = qt * 64 + wave * 16 + q4 * 4 + r;
                    int d = di * 16 + fr;  // even
                    size_t off = ((size_t)(b * SEQ + srow)) * EMB + h * HD + d;
                    __half2 h2;
                    h2.x = __float2half(o);
                    h2.y = __float2half(po);
                    *(__half2*)&CTX[off] = h2;
                }
            }
    }
}

// ---------------- output projection: out(fp32) = CTX * Wo^T ----------------
__global__ __launch_bounds__(256) void gemm_out(const __half* __restrict__ CTX,
                                                const __half* __restrict__ Wo,
                                                float* __restrict__ out) {
    __shared__ short sA[3 * 128 * 32];
    __shared__ short sB[3 * 128 * 32];
    f32x4 z = {0.f, 0.f, 0.f, 0.f};
    f32x4 acc[4][4];
#pragma unroll
    for (int i = 0; i < 4; i++)
#pragma unroll
        for (int j = 0; j < 4; j++) acc[i][j] = z;

    gemm_mainloop(CTX, Wo, blockIdx.x * 128, blockIdx.y * 128, sA, sB, acc);

    const int lane = threadIdx.x & 63;
    const int wave = threadIdx.x >> 6;
    const int wr = wave >> 1, wc = wave & 1;
    const int q4 = lane >> 4;
#pragma unroll
    for (int mi = 0; mi < 4; mi++)
#pragma unroll
        for (int ni = 0; ni < 4; ni++)
#pragma unroll
            for (int r = 0; r < 4; r++) {
                int m = blockIdx.x * 128 + wr * 64 + mi * 16 + q4 * 4 + r;
                int n = blockIdx.y * 128 + wc * 64 + ni * 16 + (lane & 15);
                out[(size_t)m * EMB + n] = acc[mi][ni][r];
            }
}

extern "C" void kernel_launch(void* const* d_in, const int* in_sizes, int n_in,
                              void* d_out, int out_size, void* d_ws, size_t ws_size,
                              hipStream_t stream) {
    const float* x  = (const float*)d_in[0];
    const float* Wq = (const float*)d_in[1];
    const float* Wk = (const float*)d_in[2];
    const float* Wv = (const float*)d_in[3];
    const float* Wo = (const float*)d_in[4];
    float* out = (float*)d_out;

    char* ws = (char*)d_ws;
    size_t off = 0;
    const size_t QKV_ELEMS = (size_t)MROWS * EMB;   // 16777216
    __half* Xh  = (__half*)(ws + off); off += QKV_ELEMS * 2;          // reused as CTX
    __half* Wqh = (__half*)(ws + off); off += (size_t)EMB * EMB * 2;
    __half* Wkh = (__half*)(ws + off); off += (size_t)EMB * EMB * 2;
    __half* Wvh = (__half*)(ws + off); off += (size_t)EMB * EMB * 2;
    __half* Woh = (__half*)(ws + off); off += (size_t)EMB * EMB * 2;
    __half* Qb  = (__half*)(ws + off); off += QKV_ELEMS * 2;
    __half* Kb  = (__half*)(ws + off); off += QKV_ELEMS * 2;
    __half* Vtb = (__half*)(ws + off); off += QKV_ELEMS * 2;
    __half* Cb  = Xh;   // X dead after gemm_qkv

    cvt_all<<<32768, 256, 0, stream>>>(x, Wq, Wk, Wv, Wo, Xh, Wqh, Wkh, Wvh, Woh);

    gemm_qkv<<<dim3(64, 48), 256, 0, stream>>>(Xh, Wqh, Wkh, Wvh, Qb, Kb, Vtb);
    attn_kernel<<<dim3(16, 64), 256, 0, stream>>>(Qb, Kb, Vtb, Cb);
    gemm_out<<<dim3(64, 16), 256, 0, stream>>>(Cb, Woh, out);
}

// Round 7
// 741.862 us; speedup vs baseline: 1.4686x; 1.0475x over previous
//
#include <hip/hip_runtime.h>
#include <hip/hip_fp16.h>

#define EMB 2048
#define NH 16
#define HD 128
#define BATCH 4
#define SEQ 2048
#define MROWS (BATCH * SEQ)   // 8192

typedef __attribute__((ext_vector_type(8))) _Float16 f16x8;
typedef __attribute__((ext_vector_type(4))) _Float16 f16x4;
typedef __attribute__((ext_vector_type(4))) float f32x4;

typedef __attribute__((address_space(3))) unsigned int lds_u32_t;
typedef const __attribute__((address_space(1))) unsigned int glb_u32_t;

__device__ __forceinline__ void async_copy16(void* lds, const void* g) {
    __builtin_amdgcn_global_load_lds((glb_u32_t*)g, (lds_u32_t*)lds, 16, 0, 0);
}

// ---------------- fused fp32 -> fp16 convert (all 5 tensors, one launch) ----------------
__global__ void cvt_all(const float* __restrict__ x,  const float* __restrict__ wq,
                        const float* __restrict__ wk, const float* __restrict__ wv,
                        const float* __restrict__ wo,
                        __half* __restrict__ xh,  __half* __restrict__ wqh,
                        __half* __restrict__ wkh, __half* __restrict__ wvh,
                        __half* __restrict__ woh) {
    int bid = blockIdx.x;
    const float* s;
    __half* d;
    int idx;
    if (bid < 16384) {
        s = x; d = xh; idx = bid * 256 + threadIdx.x;
    } else {
        int b2 = bid - 16384;
        int w = b2 >> 12;
        s = (w == 0) ? wq : (w == 1) ? wk : (w == 2) ? wv : wo;
        d = (w == 0) ? wqh : (w == 1) ? wkh : (w == 2) ? wvh : woh;
        idx = (b2 & 4095) * 256 + threadIdx.x;
    }
    float4 v = ((const float4*)s)[idx];
    __half2 a, b;
    a.x = __float2half(v.x); a.y = __float2half(v.y);
    b.x = __float2half(v.z); b.y = __float2half(v.w);
    ((__half2*)d)[2 * idx]     = a;
    ((__half2*)d)[2 * idx + 1] = b;
}

// ---------------- pipelined GEMM mainloop: C(128x128) = A * B^T, K = 2048 ----------------
// BK=32, THREE LDS buffers, depth-2 prefetch, counted vmcnt + raw s_barrier
// (loads stay in flight across the barrier). Verified round 5: conflicts 0,
// gemm_qkv < 292 us.
__device__ __forceinline__ void gemm_mainloop(const __half* __restrict__ A,
                                              const __half* __restrict__ B,
                                              int m0, int n0,
                                              short* sA, short* sB,   // each [3][128*32]
                                              f32x4 acc[4][4]) {
    const int tid  = threadIdx.x;
    const int wave = tid >> 6;
    const int lane = tid & 63;
    const int wr = wave >> 1, wc = wave & 1;
    const int frow = lane & 15;
    const int q4   = lane >> 4;                 // k-chunk 0..3 (8 halfs each)
    const int r0   = tid >> 2;                  // 0..63: staging row within 64-row group
    const int csw  = ((tid & 3) ^ (r0 & 3)) * 16;  // pre-swizzled source chunk (bytes)
    const char* gA = (const char*)A + (size_t)(m0 + r0) * (EMB * 2) + csw;
    const char* gB = (const char*)B + (size_t)(n0 + r0) * (EMB * 2) + csw;
    const size_t rstep = (size_t)64 * EMB * 2;  // +64 rows
    char* lA = (char*)sA;
    char* lB = (char*)sB;
    const int ldst = tid * 16;                  // linear LDS dest (uniform + lane*16)

#define STAGE_TILE(t, b) do {                                          \
        size_t ko = (size_t)(t) * 64;                                  \
        async_copy16(lA + (b) * 8192 + ldst,        gA + ko);          \
        async_copy16(lA + (b) * 8192 + 4096 + ldst, gA + rstep + ko);  \
        async_copy16(lB + (b) * 8192 + ldst,        gB + ko);          \
        async_copy16(lB + (b) * 8192 + 4096 + ldst, gB + rstep + ko);  \
    } while (0)

    const int nt = EMB / 32;   // 64 K-tiles
    STAGE_TILE(0, 0);
    STAGE_TILE(1, 1);

    int cb = 0;
    for (int t = 0; t < nt; ++t) {
        if (t < nt - 1) asm volatile("s_waitcnt vmcnt(4)" ::: "memory");
        else            asm volatile("s_waitcnt vmcnt(0)" ::: "memory");
        asm volatile("" ::: "memory");
        __builtin_amdgcn_s_barrier();
        asm volatile("" ::: "memory");

        const short* bufA = sA + cb * 4096;
        const short* bufB = sB + cb * 4096;
        f16x8 af[4], bf[4];
        const int slot = (q4 ^ (frow & 3)) * 8;
#pragma unroll
        for (int i = 0; i < 4; i++)
            af[i] = *(const f16x8*)&bufA[(wr * 64 + i * 16 + frow) * 32 + slot];
#pragma unroll
        for (int i = 0; i < 4; i++)
            bf[i] = *(const f16x8*)&bufB[(wc * 64 + i * 16 + frow) * 32 + slot];
#pragma unroll
        for (int mi = 0; mi < 4; mi++)
#pragma unroll
            for (int ni = 0; ni < 4; ni++)
                acc[mi][ni] = __builtin_amdgcn_mfma_f32_16x16x32_f16(af[mi], bf[ni], acc[mi][ni], 0, 0, 0);

        if (t + 2 < nt) {
            int sb = cb + 2; if (sb >= 3) sb -= 3;
            STAGE_TILE(t + 2, sb);
        }
        cb = (cb == 2) ? 0 : cb + 1;
    }
#undef STAGE_TILE
}

// ---------------- QKV projection + RoPE; Q,K -> (B,H,S,D), V -> (B,H,D,S) ----------------
__global__ __launch_bounds__(256) void gemm_qkv(const __half* __restrict__ X,
                                                const __half* __restrict__ Wq,
                                                const __half* __restrict__ Wk,
                                                const __half* __restrict__ Wv,
                                                __half* __restrict__ Q,
                                                __half* __restrict__ K,
                                                __half* __restrict__ Vt) {
    __shared__ short sA[3 * 128 * 32];
    __shared__ short sB[3 * 128 * 32];
    const int mblk = blockIdx.x;
    const int nb   = blockIdx.y;
    const int wsel = nb >> 4;
    const int nloc = (nb & 15) * 128;
    const __half* W = (wsel == 0) ? Wq : ((wsel == 1) ? Wk : Wv);

    f32x4 z = {0.f, 0.f, 0.f, 0.f};
    f32x4 acc[4][4];
#pragma unroll
    for (int i = 0; i < 4; i++)
#pragma unroll
        for (int j = 0; j < 4; j++) acc[i][j] = z;

    gemm_mainloop(X, W, mblk * 128, nloc, sA, sB, acc);

    const int lane = threadIdx.x & 63;
    const int wave = threadIdx.x >> 6;
    const int wr = wave >> 1, wc = wave & 1;
    const int q4 = lane >> 4;

    if (wsel == 2) {
        // V: write transposed directly, Vt[bh][d][s].
#pragma unroll
        for (int ni = 0; ni < 4; ni++) {
            int n = nloc + wc * 64 + ni * 16 + (lane & 15);
            int h = n >> 7, d = n & 127;
#pragma unroll
            for (int mi = 0; mi < 4; mi++) {
                int m = mblk * 128 + wr * 64 + mi * 16 + q4 * 4;
                int b = m >> 11, s = m & 2047;
                f16x4 hv;
#pragma unroll
                for (int r = 0; r < 4; r++) hv[r] = (_Float16)acc[mi][ni][r];
                *(f16x4*)(Vt + ((size_t)(b * NH + h) * HD + d) * SEQ + s) = hv;
            }
        }
        return;
    }

    __half* Obuf = (wsel == 0) ? Q : K;
#pragma unroll
    for (int ni = 0; ni < 4; ni++) {
        int n = nloc + wc * 64 + ni * 16 + (lane & 15);
        int h = n >> 7, d = n & 127;
        float invf = __expf(-((float)(d & ~1)) * (9.210340371976184f / 128.0f));
#pragma unroll
        for (int mi = 0; mi < 4; mi++) {
#pragma unroll
            for (int r = 0; r < 4; r++) {
                int m = mblk * 128 + wr * 64 + mi * 16 + q4 * 4 + r;
                int b = m >> 11, s = m & 2047;
                float v = acc[mi][ni][r];
                float p = __shfl_xor(v, 1);
                float ang = (float)s * invf;
                float sn, cs;
                __sincosf(ang, &sn, &cs);
                float res;
                if ((lane & 1) == 0) res = v * cs - p * sn;
                else                 res = v * cs + p * sn;
                float pr = __shfl_xor(res, 1);
                if ((lane & 1) == 0) {
                    __half2 hv;
                    hv.x = __float2half(res);
                    hv.y = __float2half(pr);
                    size_t off = ((size_t)(b * NH + h) * SEQ + s) * HD + d;
                    *(__half2*)(Obuf + off) = hv;
                }
            }
        }
    }
}

// ---------------- causal flash attention v6 ----------------
// Round-5 post-mortem: (256,3) code is resident at 3 blocks/CU = 768 slots;
// the 1024-block grid ran TWO rounds (occupancy 37.5% then 12.5%, avg 25.4%
// = measured). Fix: 768 blocks = 12 per head, each with an equal-work list
// of q-tiles (44 iterations each): ten pairs (31,11)..(22,20) + {21,10,9,0}
// + {8..1}. One residency round, zero tail. Hot-loop code unchanged
// ((256,3), VGPR 84, no spill). XCD mapping: 96 consecutive blocks
// (= 8 heads) per XCD.
static __device__ const signed char QT_TAB[12][8] = {
    {31, 11, -1, -1, -1, -1, -1, -1},
    {30, 12, -1, -1, -1, -1, -1, -1},
    {29, 13, -1, -1, -1, -1, -1, -1},
    {28, 14, -1, -1, -1, -1, -1, -1},
    {27, 15, -1, -1, -1, -1, -1, -1},
    {26, 16, -1, -1, -1, -1, -1, -1},
    {25, 17, -1, -1, -1, -1, -1, -1},
    {24, 18, -1, -1, -1, -1, -1, -1},
    {23, 19, -1, -1, -1, -1, -1, -1},
    {22, 20, -1, -1, -1, -1, -1, -1},
    {21, 10,  9,  0, -1, -1, -1, -1},
    { 8,  7,  6,  5,  4,  3,  2,  1},
};

__global__ __launch_bounds__(256, 3) void attn_kernel(const __half* __restrict__ Q,
                                                      const __half* __restrict__ K,
                                                      const __half* __restrict__ Vt,
                                                      __half* __restrict__ CTX) {
    __shared__ short sK[64 * 128];      // K tile: 64 keys x 128 d, 16-chunk swizzle
    __shared__ short sV[128 * 64];      // V^T tile: 128 d x 64 keys, 8-chunk swizzle
    __shared__ short sP[4][16 * 64];    // per-wave P scratch
    const int disp  = blockIdx.y * 12 + blockIdx.x;   // 0..767, dispatch order
    const int wid   = (disp & 7) * 96 + (disp >> 3);  // bijective, 96 blocks per XCD
    const int jj    = wid % 12;                       // work-list index
    const int bh    = wid / 12;                       // 0..63 (8 heads per XCD)
    const int b = bh >> 4, h = bh & 15;
    const int tid = threadIdx.x;
    const int wave = tid >> 6, lane = tid & 63;
    const int fr = lane & 15, q4 = lane >> 4;
    const size_t headoff = (size_t)bh * SEQ * HD;
    const __half* Qh = Q + headoff;
    const __half* Kh = K + headoff;
    const __half* Vth = Vt + headoff;   // [d][s]
    short* sPw = &sP[wave][0];

    f32x4 z = {0.f, 0.f, 0.f, 0.f};

#pragma unroll 1
    for (int seg = 0; seg < 8; seg++) {
        const int qt = QT_TAB[jj][seg];
        if (qt < 0) break;
        const int nk = qt + 1;

        // Q fragments (wave rows qt*64 + wave*16 + fr), scale folded
        f16x8 qf[4];
#pragma unroll
        for (int ds = 0; ds < 4; ds++) {
            qf[ds] = *(const f16x8*)(Qh + (size_t)(qt * 64 + wave * 16 + fr) * HD + ds * 32 + q4 * 8);
            qf[ds] = qf[ds] * (_Float16)0.08838834764831845f;
        }

        f32x4 accO[8];
#pragma unroll
        for (int i = 0; i < 8; i++) accO[i] = z;
        float mrow[4], lrow[4];
#pragma unroll
        for (int r = 0; r < 4; r++) { mrow[r] = -INFINITY; lrow[r] = 0.f; }

        // prefetch registers (tile 0)
        f16x8 kpre[4], vpre[4];
#pragma unroll
        for (int j = 0; j < 4; j++) {
            int id = j * 256 + tid;
            int row = id >> 4, c = id & 15;
            kpre[j] = *(const f16x8*)(Kh + (size_t)row * HD + c * 8);
        }
#pragma unroll
        for (int j = 0; j < 4; j++) {
            int id = j * 256 + tid;
            int d = id >> 3, c = id & 7;
            vpre[j] = *(const f16x8*)(Vth + (size_t)d * SEQ + c * 8);
        }

        for (int kt = 0; kt < nk; kt++) {
            __syncthreads();   // barrier A: previous compute done reading sK/sV
            // ---- VGPR -> LDS (swizzled) ----
#pragma unroll
            for (int j = 0; j < 4; j++) {
                int id = j * 256 + tid;
                int row = id >> 4, c = id & 15;
                *(f16x8*)&sK[row * 128 + ((c ^ (row & 15)) * 8)] = kpre[j];
            }
#pragma unroll
            for (int j = 0; j < 4; j++) {
                int id = j * 256 + tid;
                int d = id >> 3, c = id & 7;
                *(f16x8*)&sV[d * 64 + ((c ^ (d & 7)) * 8)] = vpre[j];
            }
            __syncthreads();   // barrier B: tiles visible

            // ---- issue next tile's global loads (overlap with compute) ----
            if (kt + 1 < nk) {
                int kbase = (kt + 1) * 64;
#pragma unroll
                for (int j = 0; j < 4; j++) {
                    int id = j * 256 + tid;
                    int row = id >> 4, c = id & 15;
                    kpre[j] = *(const f16x8*)(Kh + (size_t)(kbase + row) * HD + c * 8);
                }
#pragma unroll
                for (int j = 0; j < 4; j++) {
                    int id = j * 256 + tid;
                    int d = id >> 3, c = id & 7;
                    vpre[j] = *(const f16x8*)(Vth + (size_t)d * SEQ + kbase + c * 8);
                }
            }

            // ---- S = Q K^T (16 rows x 64 cols per wave) ----
            f32x4 accS[4];
#pragma unroll
            for (int i = 0; i < 4; i++) accS[i] = z;
            __builtin_amdgcn_s_setprio(1);
#pragma unroll
            for (int ds = 0; ds < 4; ds++) {
                f16x8 kf[4];
#pragma unroll
                for (int ni = 0; ni < 4; ni++)
                    kf[ni] = *(const f16x8*)&sK[(ni * 16 + fr) * 128 + (((ds * 4 + q4) ^ fr) * 8)];
#pragma unroll
                for (int ni = 0; ni < 4; ni++)
                    accS[ni] = __builtin_amdgcn_mfma_f32_16x16x32_f16(qf[ds], kf[ni], accS[ni], 0, 0, 0);
            }
            __builtin_amdgcn_s_setprio(0);

            // ---- causal mask (diagonal tile only) ----
            if (kt == qt) {
#pragma unroll
                for (int ni = 0; ni < 4; ni++) {
                    int kcol = ni * 16 + fr;
#pragma unroll
                    for (int r = 0; r < 4; r++) {
                        int qrow = wave * 16 + q4 * 4 + r;
                        if (kcol > qrow) accS[ni][r] = -INFINITY;
                    }
                }
            }

            // ---- online softmax ----
#pragma unroll
            for (int r = 0; r < 4; r++) {
                float mold = mrow[r];
                float mx = mold;
#pragma unroll
                for (int ni = 0; ni < 4; ni++) mx = fmaxf(mx, accS[ni][r]);
#pragma unroll
                for (int off = 1; off < 16; off <<= 1)
                    mx = fmaxf(mx, __shfl_xor(mx, off));
                float alpha = __expf(mold - mx);
                mrow[r] = mx;
                float rs = 0.f;
#pragma unroll
                for (int ni = 0; ni < 4; ni++) {
                    float p = __expf(accS[ni][r] - mx);
                    rs += p;
                    accS[ni][r] = p;
                }
#pragma unroll
                for (int off = 1; off < 16; off <<= 1)
                    rs += __shfl_xor(rs, off);
                lrow[r] = lrow[r] * alpha + rs;
#pragma unroll
                for (int di = 0; di < 8; di++)
                    accO[di][r] *= alpha;
            }

            // ---- P -> wave-private scratch (no barrier; intra-wave ordering) ----
#pragma unroll
            for (int ni = 0; ni < 4; ni++)
#pragma unroll
                for (int r = 0; r < 4; r++) {
                    float p = accS[ni][r];
                    float pp = __shfl_xor(p, 1);
                    if ((lane & 1) == 0) {
                        int row = q4 * 4 + r;
                        int col = ni * 16 + fr;                 // even
                        int xc = (col >> 3) ^ (row & 7);
                        __half2 h2;
                        h2.x = __float2half(p);
                        h2.y = __float2half(pp);
                        *(__half2*)&sPw[row * 64 + xc * 8 + (col & 7)] = h2;
                    }
                }

            // ---- O += P V ----
            __builtin_amdgcn_s_setprio(1);
#pragma unroll
            for (int ns = 0; ns < 2; ns++) {
                f16x8 pf = *(const f16x8*)&sPw[fr * 64 + (((ns * 4 + q4) ^ (fr & 7)) * 8)];
#pragma unroll
                for (int di = 0; di < 8; di++) {
                    f16x8 vf = *(const f16x8*)&sV[(di * 16 + fr) * 64 + (((ns * 4 + q4) ^ (fr & 7)) * 8)];
                    accO[di] = __builtin_amdgcn_mfma_f32_16x16x32_f16(pf, vf, accO[di], 0, 0, 0);
                }
            }
            __builtin_amdgcn_s_setprio(0);
            // no barrier here: next iteration's barrier A protects sK/sV
        }

        // ---- epilogue ----
        float linv[4];
#pragma unroll
        for (int r = 0; r < 4; r++) linv[r] = 1.f / lrow[r];

#pragma unroll
        for (int di = 0; di < 8; di++)
#pragma unroll
            for (int r = 0; r < 4; r++) {
                float o = accO[di][r] * linv[r];
                float po = __shfl_xor(o, 1);
                if ((lane & 1) == 0) {
                    int srow = qt * 64 + wave * 16 + q4 * 4 + r;
                    int d = di * 16 + fr;  // even
                    size_t off = ((size_t)(b * SEQ + srow)) * EMB + h * HD + d;
                    __half2 h2;
                    h2.x = __float2half(o);
                    h2.y = __float2half(po);
                    *(__half2*)&CTX[off] = h2;
                }
            }
    }
}

// ---------------- output projection: out(fp32) = CTX * Wo^T ----------------
__global__ __launch_bounds__(256) void gemm_out(const __half* __restrict__ CTX,
                                                const __half* __restrict__ Wo,
                                                float* __restrict__ out) {
    __shared__ short sA[3 * 128 * 32];
    __shared__ short sB[3 * 128 * 32];
    f32x4 z = {0.f, 0.f, 0.f, 0.f};
    f32x4 acc[4][4];
#pragma unroll
    for (int i = 0; i < 4; i++)
#pragma unroll
        for (int j = 0; j < 4; j++) acc[i][j] = z;

    gemm_mainloop(CTX, Wo, blockIdx.x * 128, blockIdx.y * 128, sA, sB, acc);

    const int lane = threadIdx.x & 63;
    const int wave = threadIdx.x >> 6;
    const int wr = wave >> 1, wc = wave & 1;
    const int q4 = lane >> 4;
#pragma unroll
    for (int mi = 0; mi < 4; mi++)
#pragma unroll
        for (int ni = 0; ni < 4; ni++)
#pragma unroll
            for (int r = 0; r < 4; r++) {
                int m = blockIdx.x * 128 + wr * 64 + mi * 16 + q4 * 4 + r;
                int n = blockIdx.y * 128 + wc * 64 + ni * 16 + (lane & 15);
                out[(size_t)m * EMB + n] = acc[mi][ni][r];
            }
}

extern "C" void kernel_launch(void* const* d_in, const int* in_sizes, int n_in,
                              void* d_out, int out_size, void* d_ws, size_t ws_size,
                              hipStream_t stream) {
    const float* x  = (const float*)d_in[0];
    const float* Wq = (const float*)d_in[1];
    const float* Wk = (const float*)d_in[2];
    const float* Wv = (const float*)d_in[3];
    const float* Wo = (const float*)d_in[4];
    float* out = (float*)d_out;

    char* ws = (char*)d_ws;
    size_t off = 0;
    const size_t QKV_ELEMS = (size_t)MROWS * EMB;   // 16777216
    __half* Xh  = (__half*)(ws + off); off += QKV_ELEMS * 2;          // reused as CTX
    __half* Wqh = (__half*)(ws + off); off += (size_t)EMB * EMB * 2;
    __half* Wkh = (__half*)(ws + off); off += (size_t)EMB * EMB * 2;
    __half* Wvh = (__half*)(ws + off); off += (size_t)EMB * EMB * 2;
    __half* Woh = (__half*)(ws + off); off += (size_t)EMB * EMB * 2;
    __half* Qb  = (__half*)(ws + off); off += QKV_ELEMS * 2;
    __half* Kb  = (__half*)(ws + off); off += QKV_ELEMS * 2;
    __half* Vtb = (__half*)(ws + off); off += QKV_ELEMS * 2;
    __half* Cb  = Xh;   // X dead after gemm_qkv

    cvt_all<<<32768, 256, 0, stream>>>(x, Wq, Wk, Wv, Wo, Xh, Wqh, Wkh, Wvh, Woh);

    gemm_qkv<<<dim3(64, 48), 256, 0, stream>>>(Xh, Wqh, Wkh, Wvh, Qb, Kb, Vtb);
    attn_kernel<<<dim3(12, 64), 256, 0, stream>>>(Qb, Kb, Vtb, Cb);
    gemm_out<<<dim3(64, 16), 256, 0, stream>>>(Cb, Woh, out);
}